// Round 1
// baseline (5216.523 us; speedup 1.0000x reference)
//
#include <hip/hip_runtime.h>
#include <hip/hip_bf16.h>

#define B_ 32
#define T_ 512
#define L_ 16
#define F_ 128
#define H_ 128
#define C_ 61
#define NF_ (B_*T_)   // 16384 frames

typedef unsigned int u32;
typedef unsigned short u16;

__device__ __forceinline__ float bflo(u32 v){ return __uint_as_float(v << 16); }
__device__ __forceinline__ float bfhi(u32 v){ return __uint_as_float(v & 0xffff0000u); }
__device__ __forceinline__ u16 f2bf(float f){
  u32 u = __float_as_uint(f);
  u += 0x7fffu + ((u >> 16) & 1u);
  return (u16)(u >> 16);
}
__device__ __forceinline__ u32 pack2(float a, float b){
  return (u32)f2bf(a) | ((u32)f2bf(b) << 16);
}
__device__ __forceinline__ float fast_tanh(float x){
  float e = __expf(2.f*x);
  return 1.f - 2.f/(e + 1.f);       // +inf -> 1, 0 -> -1 : no NaN
}
__device__ __forceinline__ float fast_sigmoid(float x){
  return 1.f/(1.f + __expf(-x));
}

// ---------------------------------------------------------------------------
// rnn1 layer 0: per-frame bidirectional tanh-RNN over L=16, din=F=128, H=128.
// One launch handles one direction per blockIdx.y. 4 frames per 512-thread WG,
// thread t -> (frame f = t&3, unit u = t>>2) so a wave spans 4 frames x 16
// units => weight LDS reads are 16 distinct addrs/wave (4-way multicast).
// Weights fp32 in LDS ([k4][u][4] so each unit reads contiguous 16B),
// x staged bf16-packed. Writes full sequence out (nf,16,256) bf16.
// ---------------------------------------------------------------------------
__global__ __launch_bounds__(512) void l0_kernel(
    const float* __restrict__ x,      // (nf,16,128) chunk base
    const float* __restrict__ Wih,    // (2,128,128)
    const float* __restrict__ Whh,    // (2,128,128)
    const float* __restrict__ bih,    // (2,128)
    const float* __restrict__ bhh,    // (2,128)
    u16* __restrict__ out,            // (nf,16,256) bf16
    int nframes)
{
  __shared__ __align__(16) float Wi[32][128][4];   // 64 KB
  __shared__ __align__(16) float Wh[32][128][4];   // 64 KB
  __shared__ __align__(16) uint2 xs[4][16][32];    // 16 KB (bf16 x4 packed)
  __shared__ __align__(16) float hb[2][4][128];    // 4 KB
  const int t = threadIdx.x;
  const int dir = blockIdx.y;
  const float* Wid = Wih + dir*16384;
  const float* Whd = Whh + dir*16384;
  for (int idx = t; idx < 16384; idx += 512){
    int u = idx >> 7, k = idx & 127;
    Wi[k>>2][u][k&3] = Wid[idx];
    Wh[k>>2][u][k&3] = Whd[idx];
  }
  const int f0 = blockIdx.x * 4;
  for (int idx = t; idx < 4*16*32; idx += 512){
    int f = idx >> 9;            // 512 quads per frame
    int r = idx & 511;           // r = s*32 + k4
    int gf = f0 + f;
    if (gf < nframes){
      const float4 v = *(const float4*)&x[(size_t)gf*2048 + (size_t)r*4];
      xs[f][r>>5][r&31] = make_uint2(pack2(v.x, v.y), pack2(v.z, v.w));
    }
  }
  const int f = t & 3, u = t >> 2;
  const float bsv = bih[dir*128+u] + bhh[dir*128+u];
  const bool active = (f0 + f) < nframes;
  hb[0][f][u] = 0.f;
  __syncthreads();
  int cur = 0;
  for (int st = 0; st < 16; st++){
    const int s = dir ? (15 - st) : st;
    float s0=0.f, s1=0.f, s2=0.f, s3=0.f;
    #pragma unroll
    for (int k4 = 0; k4 < 32; k4++){
      const float4 w = *(const float4*)&Wi[k4][u][0];
      const uint2 xv = xs[f][s][k4];
      s0 = fmaf(w.x, bflo(xv.x), s0);
      s1 = fmaf(w.y, bfhi(xv.x), s1);
      s2 = fmaf(w.z, bflo(xv.y), s2);
      s3 = fmaf(w.w, bfhi(xv.y), s3);
    }
    #pragma unroll
    for (int k4 = 0; k4 < 32; k4++){
      const float4 w = *(const float4*)&Wh[k4][u][0];
      const float4 hv = *(const float4*)&hb[cur][f][k4*4];
      s0 = fmaf(w.x, hv.x, s0);
      s1 = fmaf(w.y, hv.y, s1);
      s2 = fmaf(w.z, hv.z, s2);
      s3 = fmaf(w.w, hv.w, s3);
    }
    const float hn = fast_tanh(bsv + s0 + s1 + s2 + s3);
    hb[cur^1][f][u] = hn;
    cur ^= 1;
    if (active) out[(size_t)(f0+f)*4096 + s*256 + dir*128 + u] = f2bf(hn);
    __syncthreads();
  }
}

// ---------------------------------------------------------------------------
// rnn1 layer 1, FORWARD direction only (backward at s=15 is a single-step
// GEMM handled by gemm_bt). Input = l0 output (nf,16,256) bf16. K=256 input
// projection is done in two 64KB weight phases (LDS reuse), xw kept in LDS.
// Only h at s=15 is needed -> write (nf,128) slice of rnn1out.
// ---------------------------------------------------------------------------
__global__ __launch_bounds__(512) void l1f_kernel(
    const u16* __restrict__ U,        // (nf,16,256) bf16
    const float* __restrict__ Wih,    // (2,128,256), use dir0
    const float* __restrict__ Whh,    // (2,128,128), dir0
    const float* __restrict__ bih,    // (2,128)
    const float* __restrict__ bhh,
    u16* __restrict__ out,            // rnn1out rows, cols 0..127 (ld 256)
    int nframes)                      // multiple of 4
{
  __shared__ __align__(16) float Wb[32][128][4];   // 64 KB, re-staged 3x
  __shared__ __align__(16) uint2 us[4][16][64];    // 32 KB (bf16 input)
  __shared__ __align__(16) float xwl[4][16][128];  // 32 KB
  __shared__ __align__(16) float hb[2][4][128];    // 4 KB
  const int t = threadIdx.x;
  const int f0 = blockIdx.x * 4;
  {
    const uint2* U2 = (const uint2*)(U + (size_t)f0*4096);
    uint2* ud = &us[0][0][0];
    for (int idx = t; idx < 4096; idx += 512) ud[idx] = U2[idx];
  }
  for (int idx = t; idx < 16384; idx += 512){
    int u = idx >> 7, k = idx & 127;
    Wb[k>>2][u][k&3] = Wih[(size_t)u*256 + k];
  }
  const int f = t & 3, u = t >> 2;
  const float bsv = bih[u] + bhh[u];
  __syncthreads();
  for (int s = 0; s < 16; s++){
    float s0=0,s1=0,s2=0,s3=0;
    #pragma unroll
    for (int k4 = 0; k4 < 32; k4++){
      const float4 w = *(const float4*)&Wb[k4][u][0];
      const uint2 uv = us[f][s][k4];
      s0 = fmaf(w.x, bflo(uv.x), s0);
      s1 = fmaf(w.y, bfhi(uv.x), s1);
      s2 = fmaf(w.z, bflo(uv.y), s2);
      s3 = fmaf(w.w, bfhi(uv.y), s3);
    }
    xwl[f][s][u] = bsv + s0+s1+s2+s3;
  }
  __syncthreads();
  for (int idx = t; idx < 16384; idx += 512){
    int u2 = idx >> 7, k = idx & 127;
    Wb[k>>2][u2][k&3] = Wih[(size_t)u2*256 + 128 + k];
  }
  __syncthreads();
  for (int s = 0; s < 16; s++){
    float s0=0,s1=0,s2=0,s3=0;
    #pragma unroll
    for (int k4 = 0; k4 < 32; k4++){
      const float4 w = *(const float4*)&Wb[k4][u][0];
      const uint2 uv = us[f][s][32+k4];
      s0 = fmaf(w.x, bflo(uv.x), s0);
      s1 = fmaf(w.y, bfhi(uv.x), s1);
      s2 = fmaf(w.z, bflo(uv.y), s2);
      s3 = fmaf(w.w, bfhi(uv.y), s3);
    }
    xwl[f][s][u] += s0+s1+s2+s3;
  }
  __syncthreads();
  for (int idx = t; idx < 16384; idx += 512){
    int u2 = idx >> 7, k = idx & 127;
    Wb[k>>2][u2][k&3] = Whh[(size_t)u2*128 + k];
  }
  hb[0][f][u] = 0.f;
  __syncthreads();
  int cur = 0;
  for (int st = 0; st < 16; st++){
    float s0=0,s1=0,s2=0,s3=0;
    #pragma unroll
    for (int k4 = 0; k4 < 32; k4++){
      const float4 w = *(const float4*)&Wb[k4][u][0];
      const float4 hv = *(const float4*)&hb[cur][f][k4*4];
      s0 = fmaf(w.x, hv.x, s0);
      s1 = fmaf(w.y, hv.y, s1);
      s2 = fmaf(w.z, hv.z, s2);
      s3 = fmaf(w.w, hv.w, s3);
    }
    const float hn = fast_tanh(xwl[f][st][u] + s0+s1+s2+s3);
    hb[cur^1][f][u] = hn;
    cur ^= 1;
    if (st == 15) out[(size_t)(f0+f)*256 + u] = f2bf(hn);
    __syncthreads();
  }
}

// ---------------------------------------------------------------------------
// Generic C = A(bf16, M x K) @ B^T(f32, N x K) + bias (+bias2) [+tanh],
// output fp32 (Cf) or bf16 (Cb), 64x64 tile, 4x4 per thread.
// ---------------------------------------------------------------------------
__global__ __launch_bounds__(256) void gemm_bt(
    const u16* __restrict__ A, int lda2,     // lda/2 in u32 units
    const float* __restrict__ Bm, int K,
    const float* __restrict__ bias, const float* __restrict__ bias2,
    float* __restrict__ Cf, u16* __restrict__ Cb, int ldc, int act)
{
  __shared__ __align__(16) float As[32][68];
  __shared__ __align__(16) float Bs[32][68];
  const int t = threadIdx.x;
  const int n0 = blockIdx.x * 64, m0 = blockIdx.y * 64;
  const int tx = t & 15, ty = t >> 4;
  float acc[4][4] = {{0.f}};
  const u32* A32 = (const u32*)A;
  for (int kc = 0; kc < K; kc += 32){
    #pragma unroll
    for (int i = 0; i < 4; i++){
      int li = t + 256*i;
      int m = li >> 4, kp = li & 15;
      u32 v = A32[(size_t)(m0+m)*lda2 + (kc>>1) + kp];
      As[2*kp][m]   = bflo(v);
      As[2*kp+1][m] = bfhi(v);
    }
    #pragma unroll
    for (int i = 0; i < 8; i++){
      int li = t + 256*i;
      int n = li >> 5, k = li & 31;
      Bs[k][n] = Bm[(size_t)(n0+n)*K + kc + k];
    }
    __syncthreads();
    #pragma unroll
    for (int k = 0; k < 32; k++){
      const float4 a = *(const float4*)&As[k][ty*4];
      const float4 b = *(const float4*)&Bs[k][tx*4];
      const float av[4] = {a.x,a.y,a.z,a.w};
      const float bv[4] = {b.x,b.y,b.z,b.w};
      #pragma unroll
      for (int i=0;i<4;i++)
        #pragma unroll
        for (int j=0;j<4;j++)
          acc[i][j] = fmaf(av[i], bv[j], acc[i][j]);
    }
    __syncthreads();
  }
  float bcol[4];
  #pragma unroll
  for (int j=0;j<4;j++){
    int n = n0 + tx*4 + j;
    float bv = bias[n];
    if (bias2) bv += bias2[n];
    bcol[j] = bv;
  }
  #pragma unroll
  for (int i=0;i<4;i++){
    int m = m0 + ty*4 + i;
    float v0 = acc[i][0]+bcol[0], v1 = acc[i][1]+bcol[1];
    float v2 = acc[i][2]+bcol[2], v3 = acc[i][3]+bcol[3];
    if (act){ v0=fast_tanh(v0); v1=fast_tanh(v1); v2=fast_tanh(v2); v3=fast_tanh(v3); }
    if (Cf){
      *(float4*)&Cf[(size_t)m*ldc + n0 + tx*4] = make_float4(v0,v1,v2,v3);
    } else {
      uint2 o = make_uint2(pack2(v0,v1), pack2(v2,v3));
      *(uint2*)&Cb[(size_t)m*ldc + n0 + tx*4] = o;
    }
  }
}

// ---------------------------------------------------------------------------
// GRU recurrence: one WG per (batch b, direction). 384 threads = one gate
// output each (r|z|n packing). Whh bf16-packed in LDS, h fp32 in LDS,
// xw (input projection incl. bih) precomputed by gemm_bt. T=512 steps.
// ---------------------------------------------------------------------------
__global__ __launch_bounds__(384) void gru_scan(
    const float* __restrict__ xw,   // (16384,768)
    const float* __restrict__ Whh,  // (2,384,128)
    const float* __restrict__ bhh,  // (2,384)
    u16* __restrict__ hout)         // (16384,256) bf16
{
  __shared__ __align__(16) uint2 Wp[32][384];  // 98.3 KB
  __shared__ __align__(16) float h[128];
  __shared__ float gl[384];
  __shared__ float xwl[384];
  const int t = threadIdx.x;
  const int b = blockIdx.x >> 1, dir = blockIdx.x & 1;
  const float* Wd = Whh + (size_t)dir*49152;
  for (int idx = t; idx < 12288; idx += 384){
    int o = idx >> 5, k4 = idx & 31;
    const float4 w = *(const float4*)&Wd[(size_t)o*128 + k4*4];
    Wp[k4][o] = make_uint2(pack2(w.x, w.y), pack2(w.z, w.w));
  }
  const float bh = bhh[dir*384 + t];
  if (t < 128) h[t] = 0.f;
  __syncthreads();
  for (int ti = 0; ti < 512; ti++){
    const int tt = dir ? (511 - ti) : ti;
    const size_t row = (size_t)b*512 + tt;
    const float xv = xw[row*768 + dir*384 + t];   // issued early, used late
    float s0=0,s1=0,s2=0,s3=0;
    const float4* hp = (const float4*)h;
    #pragma unroll
    for (int k4 = 0; k4 < 32; k4++){
      const uint2 wp = Wp[k4][t];
      const float4 hv = hp[k4];
      s0 = fmaf(bflo(wp.x), hv.x, s0);
      s1 = fmaf(bfhi(wp.x), hv.y, s1);
      s2 = fmaf(bflo(wp.y), hv.z, s2);
      s3 = fmaf(bfhi(wp.y), hv.w, s3);
    }
    gl[t] = bh + s0+s1+s2+s3;
    xwl[t] = xv;
    __syncthreads();
    if (t < 128){
      const float r = fast_sigmoid(xwl[t] + gl[t]);
      const float z = fast_sigmoid(xwl[128+t] + gl[128+t]);
      const float n = fast_tanh(xwl[256+t] + r*gl[256+t]);
      const float hn = (1.f - z)*n + z*h[t];
      h[t] = hn;
      hout[row*256 + dir*128 + t] = f2bf(hn);
    }
    __syncthreads();
  }
}

__global__ void prefix_kernel(const int* __restrict__ lengths, int* __restrict__ pre){
  if (threadIdx.x == 0 && blockIdx.x == 0){
    int run = 0;
    for (int b = 0; b < 32; b++){ pre[b] = run; run += lengths[b]; }
  }
}

// ---------------------------------------------------------------------------
// Final FC (61 x 256) + ragged masked scatter into d_out.
// ---------------------------------------------------------------------------
__global__ __launch_bounds__(256) void fc_kernel(
    const u16* __restrict__ A,      // (16384,256) bf16
    const float* __restrict__ W,    // (61,256)
    const float* __restrict__ bias, // (61)
    const int* __restrict__ lengths,
    const int* __restrict__ pre,
    float* __restrict__ out)
{
  __shared__ __align__(16) float4 Wl[64][61];   // [k4][c], 62.4 KB
  __shared__ __align__(16) float  Al[64][256];  // 64 KB
  const int t = threadIdx.x;
  const int row0 = blockIdx.x * 64;
  for (int idx = t; idx < 61*64; idx += 256){
    int c = idx >> 6, k4 = idx & 63;
    Wl[k4][c] = *(const float4*)&W[(size_t)c*256 + k4*4];
  }
  {
    const u32* A32 = (const u32*)(A + (size_t)row0*256);
    for (int idx = t; idx < 8192; idx += 256){
      u32 v = A32[idx];
      int r = idx >> 7, kp = idx & 127;
      Al[r][2*kp]   = bflo(v);
      Al[r][2*kp+1] = bfhi(v);
    }
  }
  __syncthreads();
  const int c = t & 63;
  const int rbase = t >> 6;
  if (c < 61){
    const float bv = bias[c];
    for (int rr = rbase; rr < 64; rr += 4){
      float s0=0,s1=0,s2=0,s3=0;
      const float4* Ap = (const float4*)&Al[rr][0];
      #pragma unroll
      for (int k4 = 0; k4 < 64; k4++){
        const float4 w = Wl[k4][c];
        const float4 a = Ap[k4];
        s0 = fmaf(w.x, a.x, s0);
        s1 = fmaf(w.y, a.y, s1);
        s2 = fmaf(w.z, a.z, s2);
        s3 = fmaf(w.w, a.w, s3);
      }
      const int n = row0 + rr;
      const int b = n >> 9, tt = n & 511;
      if (tt < lengths[b])
        out[(size_t)(pre[b] + tt)*61 + c] = bv + s0+s1+s2+s3;
    }
  }
}

extern "C" void kernel_launch(void* const* d_in, const int* in_sizes, int n_in,
                              void* d_out, int out_size, void* d_ws, size_t ws_size,
                              hipStream_t stream)
{
  const float* x     = (const float*)d_in[0];
  const int*   lens  = (const int*)d_in[1];
  const float* r0Wih = (const float*)d_in[2];
  const float* r0Whh = (const float*)d_in[3];
  const float* r0bih = (const float*)d_in[4];
  const float* r0bhh = (const float*)d_in[5];
  const float* r1Wih = (const float*)d_in[6];
  const float* r1Whh = (const float*)d_in[7];
  const float* r1bih = (const float*)d_in[8];
  const float* r1bhh = (const float*)d_in[9];
  const float* g0Wih = (const float*)d_in[10];
  const float* g0Whh = (const float*)d_in[11];
  const float* g0bih = (const float*)d_in[12];
  const float* g0bhh = (const float*)d_in[13];
  const float* g1Wih = (const float*)d_in[14];
  const float* g1Whh = (const float*)d_in[15];
  const float* g1bih = (const float*)d_in[16];
  const float* g1bhh = (const float*)d_in[17];
  const float* fcW   = (const float*)d_in[18];
  const float* fcb   = (const float*)d_in[19];
  float* out = (float*)d_out;

  // workspace layout (bytes); l0buf region is reused for GRU xw after rnn1
  char* ws = (char*)d_ws;
  u16*   l0buf = (u16*)(ws);                 // 33.6 MB (chunked) | xw 50.3 MB
  float* xwbuf = (float*)(ws);
  u16*   g0out = (u16*)(ws + 50331648);      // 8.39 MB
  u16*   g1out = (u16*)(ws + 58720256);      // 8.39 MB
  u16*   rnn1  = (u16*)(ws + 67108864);      // 8.39 MB
  int*   pre   = (int*)(ws + 75497472);      // 128 B

  const int CH = 4096;  // frames per rnn1 chunk
  for (int c = 0; c < NF_/CH; c++){
    l0_kernel<<<dim3(CH/4, 2), 512, 0, stream>>>(
        x + (size_t)c*CH*2048, r0Wih, r0Whh, r0bih, r0bhh, l0buf, CH);
    l1f_kernel<<<dim3(CH/4), 512, 0, stream>>>(
        l0buf, r1Wih, r1Whh, r1bih, r1bhh, rnn1 + (size_t)c*CH*256, CH);
    // layer1 backward @ s=15: tanh(u15 @ Wih_b^T + bih_b + bhh_b)
    gemm_bt<<<dim3(2, CH/64), 256, 0, stream>>>(
        l0buf + 15*256, 4096/2, r1Wih + 32768, 256,
        r1bih + 128, r1bhh + 128,
        (float*)nullptr, rnn1 + (size_t)c*CH*256 + 128, 256, 1);
  }
  // GRU layer 0
  gemm_bt<<<dim3(12, NF_/64), 256, 0, stream>>>(
      rnn1, 128, g0Wih, 256, g0bih, (const float*)nullptr,
      xwbuf, (u16*)nullptr, 768, 0);
  gru_scan<<<64, 384, 0, stream>>>(xwbuf, g0Whh, g0bhh, g0out);
  // GRU layer 1
  gemm_bt<<<dim3(12, NF_/64), 256, 0, stream>>>(
      g0out, 128, g1Wih, 256, g1bih, (const float*)nullptr,
      xwbuf, (u16*)nullptr, 768, 0);
  gru_scan<<<64, 384, 0, stream>>>(xwbuf, g1Whh, g1bhh, g1out);
  // FC + ragged scatter
  prefix_kernel<<<1, 64, 0, stream>>>(lens, pre);
  fc_kernel<<<NF_/64, 256, 0, stream>>>(g1out, fcW, fcb, lens, pre, out);
}

// Round 2
// 4834.422 us; speedup vs baseline: 1.0790x; 1.0790x over previous
//
#include <hip/hip_runtime.h>
#include <hip/hip_bf16.h>

#define B_ 32
#define T_ 512
#define L_ 16
#define F_ 128
#define H_ 128
#define C_ 61
#define NF_ (B_*T_)   // 16384 frames

typedef unsigned int u32;
typedef unsigned short u16;

__device__ __forceinline__ float bflo(u32 v){ return __uint_as_float(v << 16); }
__device__ __forceinline__ float bfhi(u32 v){ return __uint_as_float(v & 0xffff0000u); }
__device__ __forceinline__ u16 f2bf(float f){
  u32 u = __float_as_uint(f);
  u += 0x7fffu + ((u >> 16) & 1u);
  return (u16)(u >> 16);
}
__device__ __forceinline__ u32 pack2(float a, float b){
  return (u32)f2bf(a) | ((u32)f2bf(b) << 16);
}
__device__ __forceinline__ float fast_tanh(float x){
  float e = __expf(2.f*x);
  return 1.f - 2.f/(e + 1.f);       // +inf -> 1, 0 -> -1 : no NaN
}
__device__ __forceinline__ float fast_sigmoid(float x){
  return 1.f/(1.f + __expf(-x));
}

// ---------------------------------------------------------------------------
// rnn1 layer 0: per-frame bidirectional tanh-RNN over L=16, din=F=128, H=128.
// ---------------------------------------------------------------------------
__global__ __launch_bounds__(512) void l0_kernel(
    const float* __restrict__ x,      // (nf,16,128) chunk base
    const float* __restrict__ Wih,    // (2,128,128)
    const float* __restrict__ Whh,    // (2,128,128)
    const float* __restrict__ bih,    // (2,128)
    const float* __restrict__ bhh,    // (2,128)
    u16* __restrict__ out,            // (nf,16,256) bf16
    int nframes)
{
  __shared__ __align__(16) float Wi[32][128][4];   // 64 KB
  __shared__ __align__(16) float Wh[32][128][4];   // 64 KB
  __shared__ __align__(16) uint2 xs[4][16][32];    // 16 KB (bf16 x4 packed)
  __shared__ __align__(16) float hb[2][4][128];    // 4 KB
  const int t = threadIdx.x;
  const int dir = blockIdx.y;
  const float* Wid = Wih + dir*16384;
  const float* Whd = Whh + dir*16384;
  for (int idx = t; idx < 16384; idx += 512){
    int u = idx >> 7, k = idx & 127;
    Wi[k>>2][u][k&3] = Wid[idx];
    Wh[k>>2][u][k&3] = Whd[idx];
  }
  const int f0 = blockIdx.x * 4;
  for (int idx = t; idx < 4*16*32; idx += 512){
    int f = idx >> 9;            // 512 quads per frame
    int r = idx & 511;           // r = s*32 + k4
    int gf = f0 + f;
    if (gf < nframes){
      const float4 v = *(const float4*)&x[(size_t)gf*2048 + (size_t)r*4];
      xs[f][r>>5][r&31] = make_uint2(pack2(v.x, v.y), pack2(v.z, v.w));
    }
  }
  const int f = t & 3, u = t >> 2;
  const float bsv = bih[dir*128+u] + bhh[dir*128+u];
  const bool active = (f0 + f) < nframes;
  hb[0][f][u] = 0.f;
  __syncthreads();
  int cur = 0;
  for (int st = 0; st < 16; st++){
    const int s = dir ? (15 - st) : st;
    float s0=0.f, s1=0.f, s2=0.f, s3=0.f;
    #pragma unroll
    for (int k4 = 0; k4 < 32; k4++){
      const float4 w = *(const float4*)&Wi[k4][u][0];
      const uint2 xv = xs[f][s][k4];
      s0 = fmaf(w.x, bflo(xv.x), s0);
      s1 = fmaf(w.y, bfhi(xv.x), s1);
      s2 = fmaf(w.z, bflo(xv.y), s2);
      s3 = fmaf(w.w, bfhi(xv.y), s3);
    }
    #pragma unroll
    for (int k4 = 0; k4 < 32; k4++){
      const float4 w = *(const float4*)&Wh[k4][u][0];
      const float4 hv = *(const float4*)&hb[cur][f][k4*4];
      s0 = fmaf(w.x, hv.x, s0);
      s1 = fmaf(w.y, hv.y, s1);
      s2 = fmaf(w.z, hv.z, s2);
      s3 = fmaf(w.w, hv.w, s3);
    }
    const float hn = fast_tanh(bsv + s0 + s1 + s2 + s3);
    hb[cur^1][f][u] = hn;
    cur ^= 1;
    if (active) out[(size_t)(f0+f)*4096 + s*256 + dir*128 + u] = f2bf(hn);
    __syncthreads();
  }
}

// ---------------------------------------------------------------------------
// rnn1 layer 1, FORWARD direction only.
// ---------------------------------------------------------------------------
__global__ __launch_bounds__(512) void l1f_kernel(
    const u16* __restrict__ U,        // (nf,16,256) bf16
    const float* __restrict__ Wih,    // (2,128,256), use dir0
    const float* __restrict__ Whh,    // (2,128,128), dir0
    const float* __restrict__ bih,    // (2,128)
    const float* __restrict__ bhh,
    u16* __restrict__ out,            // rnn1out rows, cols 0..127 (ld 256)
    int nframes)                      // multiple of 4
{
  __shared__ __align__(16) float Wb[32][128][4];   // 64 KB, re-staged 3x
  __shared__ __align__(16) uint2 us[4][16][64];    // 32 KB (bf16 input)
  __shared__ __align__(16) float xwl[4][16][128];  // 32 KB
  __shared__ __align__(16) float hb[2][4][128];    // 4 KB
  const int t = threadIdx.x;
  const int f0 = blockIdx.x * 4;
  {
    const uint2* U2 = (const uint2*)(U + (size_t)f0*4096);
    uint2* ud = &us[0][0][0];
    for (int idx = t; idx < 4096; idx += 512) ud[idx] = U2[idx];
  }
  for (int idx = t; idx < 16384; idx += 512){
    int u = idx >> 7, k = idx & 127;
    Wb[k>>2][u][k&3] = Wih[(size_t)u*256 + k];
  }
  const int f = t & 3, u = t >> 2;
  const float bsv = bih[u] + bhh[u];
  __syncthreads();
  for (int s = 0; s < 16; s++){
    float s0=0,s1=0,s2=0,s3=0;
    #pragma unroll
    for (int k4 = 0; k4 < 32; k4++){
      const float4 w = *(const float4*)&Wb[k4][u][0];
      const uint2 uv = us[f][s][k4];
      s0 = fmaf(w.x, bflo(uv.x), s0);
      s1 = fmaf(w.y, bfhi(uv.x), s1);
      s2 = fmaf(w.z, bflo(uv.y), s2);
      s3 = fmaf(w.w, bfhi(uv.y), s3);
    }
    xwl[f][s][u] = bsv + s0+s1+s2+s3;
  }
  __syncthreads();
  for (int idx = t; idx < 16384; idx += 512){
    int u2 = idx >> 7, k = idx & 127;
    Wb[k>>2][u2][k&3] = Wih[(size_t)u2*256 + 128 + k];
  }
  __syncthreads();
  for (int s = 0; s < 16; s++){
    float s0=0,s1=0,s2=0,s3=0;
    #pragma unroll
    for (int k4 = 0; k4 < 32; k4++){
      const float4 w = *(const float4*)&Wb[k4][u][0];
      const uint2 uv = us[f][s][32+k4];
      s0 = fmaf(w.x, bflo(uv.x), s0);
      s1 = fmaf(w.y, bfhi(uv.x), s1);
      s2 = fmaf(w.z, bflo(uv.y), s2);
      s3 = fmaf(w.w, bfhi(uv.y), s3);
    }
    xwl[f][s][u] += s0+s1+s2+s3;
  }
  __syncthreads();
  for (int idx = t; idx < 16384; idx += 512){
    int u2 = idx >> 7, k = idx & 127;
    Wb[k>>2][u2][k&3] = Whh[(size_t)u2*128 + k];
  }
  hb[0][f][u] = 0.f;
  __syncthreads();
  int cur = 0;
  for (int st = 0; st < 16; st++){
    float s0=0,s1=0,s2=0,s3=0;
    #pragma unroll
    for (int k4 = 0; k4 < 32; k4++){
      const float4 w = *(const float4*)&Wb[k4][u][0];
      const float4 hv = *(const float4*)&hb[cur][f][k4*4];
      s0 = fmaf(w.x, hv.x, s0);
      s1 = fmaf(w.y, hv.y, s1);
      s2 = fmaf(w.z, hv.z, s2);
      s3 = fmaf(w.w, hv.w, s3);
    }
    const float hn = fast_tanh(xwl[f][st][u] + s0+s1+s2+s3);
    hb[cur^1][f][u] = hn;
    cur ^= 1;
    if (st == 15) out[(size_t)(f0+f)*256 + u] = f2bf(hn);
    __syncthreads();
  }
}

// ---------------------------------------------------------------------------
// Generic C = A(bf16, M x K) @ B^T(f32, N x K) + bias (+bias2) [+tanh]
// ---------------------------------------------------------------------------
__global__ __launch_bounds__(256) void gemm_bt(
    const u16* __restrict__ A, int lda2,     // lda/2 in u32 units
    const float* __restrict__ Bm, int K,
    const float* __restrict__ bias, const float* __restrict__ bias2,
    float* __restrict__ Cf, u16* __restrict__ Cb, int ldc, int act)
{
  __shared__ __align__(16) float As[32][68];
  __shared__ __align__(16) float Bs[32][68];
  const int t = threadIdx.x;
  const int n0 = blockIdx.x * 64, m0 = blockIdx.y * 64;
  const int tx = t & 15, ty = t >> 4;
  float acc[4][4] = {{0.f}};
  const u32* A32 = (const u32*)A;
  for (int kc = 0; kc < K; kc += 32){
    #pragma unroll
    for (int i = 0; i < 4; i++){
      int li = t + 256*i;
      int m = li >> 4, kp = li & 15;
      u32 v = A32[(size_t)(m0+m)*lda2 + (kc>>1) + kp];
      As[2*kp][m]   = bflo(v);
      As[2*kp+1][m] = bfhi(v);
    }
    #pragma unroll
    for (int i = 0; i < 8; i++){
      int li = t + 256*i;
      int n = li >> 5, k = li & 31;
      Bs[k][n] = Bm[(size_t)(n0+n)*K + kc + k];
    }
    __syncthreads();
    #pragma unroll
    for (int k = 0; k < 32; k++){
      const float4 a = *(const float4*)&As[k][ty*4];
      const float4 b = *(const float4*)&Bs[k][tx*4];
      const float av[4] = {a.x,a.y,a.z,a.w};
      const float bv[4] = {b.x,b.y,b.z,b.w};
      #pragma unroll
      for (int i=0;i<4;i++)
        #pragma unroll
        for (int j=0;j<4;j++)
          acc[i][j] = fmaf(av[i], bv[j], acc[i][j]);
    }
    __syncthreads();
  }
  float bcol[4];
  #pragma unroll
  for (int j=0;j<4;j++){
    int n = n0 + tx*4 + j;
    float bv = bias[n];
    if (bias2) bv += bias2[n];
    bcol[j] = bv;
  }
  #pragma unroll
  for (int i=0;i<4;i++){
    int m = m0 + ty*4 + i;
    float v0 = acc[i][0]+bcol[0], v1 = acc[i][1]+bcol[1];
    float v2 = acc[i][2]+bcol[2], v3 = acc[i][3]+bcol[3];
    if (act){ v0=fast_tanh(v0); v1=fast_tanh(v1); v2=fast_tanh(v2); v3=fast_tanh(v3); }
    if (Cf){
      *(float4*)&Cf[(size_t)m*ldc + n0 + tx*4] = make_float4(v0,v1,v2,v3);
    } else {
      uint2 o = make_uint2(pack2(v0,v1), pack2(v2,v3));
      *(uint2*)&Cb[(size_t)m*ldc + n0 + tx*4] = o;
    }
  }
}

// ---------------------------------------------------------------------------
// GRU recurrence: one WG per (batch b, direction). 384 threads, Whh row held
// bf16-packed in REGISTERS (32 x uint2), h fp32 in LDS (broadcast reads),
// xw loaded directly from global by gate threads, prefetched 2 steps ahead.
// Two barriers per step.
// ---------------------------------------------------------------------------
__global__ __launch_bounds__(384) void gru_scan(
    const float* __restrict__ xw,   // (16384,768)
    const float* __restrict__ Whh,  // (2,384,128)
    const float* __restrict__ bhh,  // (2,384)
    u16* __restrict__ hout)         // (16384,256) bf16
{
  __shared__ __align__(16) float h[128];
  __shared__ float gl[384];
  const int t = threadIdx.x;
  const int b = blockIdx.x >> 1, dir = blockIdx.x & 1;
  // stage own weight row into registers, bf16-packed
  uint2 wreg[32];
  {
    const float* Wd = Whh + (size_t)dir*49152 + (size_t)t*128;
    #pragma unroll
    for (int k4 = 0; k4 < 32; k4++){
      const float4 w = *(const float4*)&Wd[k4*4];
      wreg[k4] = make_uint2(pack2(w.x, w.y), pack2(w.z, w.w));
    }
  }
  const float bh = bhh[dir*384 + t];
  const float* xwb = xw + (size_t)b*512*768 + dir*384;
  float hreg = 0.f;
  float pxr0=0,pxz0=0,pxn0=0, pxr1=0,pxz1=0,pxn1=0;
  if (t < 128){
    h[t] = 0.f;
    const int t0 = dir ? 511 : 0;
    const int t1 = dir ? 510 : 1;
    pxr0 = xwb[(size_t)t0*768 + t];
    pxz0 = xwb[(size_t)t0*768 + 128 + t];
    pxn0 = xwb[(size_t)t0*768 + 256 + t];
    pxr1 = xwb[(size_t)t1*768 + t];
    pxz1 = xwb[(size_t)t1*768 + 128 + t];
    pxn1 = xwb[(size_t)t1*768 + 256 + t];
  }
  __syncthreads();

#define GRU_STEP(TI, PR, PZ, PN)                                            \
  {                                                                         \
    const int tt = dir ? (511 - (TI)) : (TI);                               \
    float s0=0,s1=0,s2=0,s3=0;                                              \
    const float4* hp = (const float4*)h;                                    \
    _Pragma("unroll")                                                       \
    for (int k4 = 0; k4 < 32; k4++){                                        \
      const uint2 wp = wreg[k4];                                            \
      const float4 hv = hp[k4];                                             \
      s0 = fmaf(bflo(wp.x), hv.x, s0);                                      \
      s1 = fmaf(bfhi(wp.x), hv.y, s1);                                      \
      s2 = fmaf(bflo(wp.y), hv.z, s2);                                      \
      s3 = fmaf(bfhi(wp.y), hv.w, s3);                                      \
    }                                                                       \
    gl[t] = bh + s0+s1+s2+s3;                                               \
    __syncthreads();                                                        \
    if (t < 128){                                                           \
      const float r = fast_sigmoid(PR + gl[t]);                             \
      const float z = fast_sigmoid(PZ + gl[128+t]);                         \
      const float n = fast_tanh(PN + r*gl[256+t]);                          \
      const float hn = (1.f - z)*n + z*hreg;                                \
      hreg = hn;                                                            \
      h[t] = hn;                                                            \
      hout[((size_t)b*512 + tt)*256 + dir*128 + t] = f2bf(hn);              \
      /* prefetch step TI+2 into the PR/PZ/PN regs just consumed */         \
      int tn = dir ? (511 - ((TI)+2)) : ((TI)+2);                           \
      tn = tn < 0 ? 0 : (tn > 511 ? 511 : tn);                              \
      const float* xp = xwb + (size_t)tn*768;                               \
      PR = xp[t]; PZ = xp[128+t]; PN = xp[256+t];                           \
    }                                                                       \
    __syncthreads();                                                        \
  }

  for (int ti = 0; ti < 512; ti += 2){
    GRU_STEP(ti,   pxr0, pxz0, pxn0);
    GRU_STEP(ti+1, pxr1, pxz1, pxn1);
  }
#undef GRU_STEP
}

__global__ void prefix_kernel(const int* __restrict__ lengths, int* __restrict__ pre){
  if (threadIdx.x == 0 && blockIdx.x == 0){
    int run = 0;
    for (int b = 0; b < 32; b++){ pre[b] = run; run += lengths[b]; }
  }
}

// ---------------------------------------------------------------------------
// Final FC (61 x 256) + ragged masked scatter into d_out.
// ---------------------------------------------------------------------------
__global__ __launch_bounds__(256) void fc_kernel(
    const u16* __restrict__ A,      // (16384,256) bf16
    const float* __restrict__ W,    // (61,256)
    const float* __restrict__ bias, // (61)
    const int* __restrict__ lengths,
    const int* __restrict__ pre,
    float* __restrict__ out)
{
  __shared__ __align__(16) float4 Wl[64][61];   // [k4][c], 62.4 KB
  __shared__ __align__(16) float  Al[64][256];  // 64 KB
  const int t = threadIdx.x;
  const int row0 = blockIdx.x * 64;
  for (int idx = t; idx < 61*64; idx += 256){
    int c = idx >> 6, k4 = idx & 63;
    Wl[k4][c] = *(const float4*)&W[(size_t)c*256 + k4*4];
  }
  {
    const u32* A32 = (const u32*)(A + (size_t)row0*256);
    for (int idx = t; idx < 8192; idx += 256){
      u32 v = A32[idx];
      int r = idx >> 7, kp = idx & 127;
      Al[r][2*kp]   = bflo(v);
      Al[r][2*kp+1] = bfhi(v);
    }
  }
  __syncthreads();
  const int c = t & 63;
  const int rbase = t >> 6;
  if (c < 61){
    const float bv = bias[c];
    for (int rr = rbase; rr < 64; rr += 4){
      float s0=0,s1=0,s2=0,s3=0;
      const float4* Ap = (const float4*)&Al[rr][0];
      #pragma unroll
      for (int k4 = 0; k4 < 64; k4++){
        const float4 w = Wl[k4][c];
        const float4 a = Ap[k4];
        s0 = fmaf(w.x, a.x, s0);
        s1 = fmaf(w.y, a.y, s1);
        s2 = fmaf(w.z, a.z, s2);
        s3 = fmaf(w.w, a.w, s3);
      }
      const int n = row0 + rr;
      const int b = n >> 9, tt = n & 511;
      if (tt < lengths[b])
        out[(size_t)(pre[b] + tt)*61 + c] = bv + s0+s1+s2+s3;
    }
  }
}

extern "C" void kernel_launch(void* const* d_in, const int* in_sizes, int n_in,
                              void* d_out, int out_size, void* d_ws, size_t ws_size,
                              hipStream_t stream)
{
  const float* x     = (const float*)d_in[0];
  const int*   lens  = (const int*)d_in[1];
  const float* r0Wih = (const float*)d_in[2];
  const float* r0Whh = (const float*)d_in[3];
  const float* r0bih = (const float*)d_in[4];
  const float* r0bhh = (const float*)d_in[5];
  const float* r1Wih = (const float*)d_in[6];
  const float* r1Whh = (const float*)d_in[7];
  const float* r1bih = (const float*)d_in[8];
  const float* r1bhh = (const float*)d_in[9];
  const float* g0Wih = (const float*)d_in[10];
  const float* g0Whh = (const float*)d_in[11];
  const float* g0bih = (const float*)d_in[12];
  const float* g0bhh = (const float*)d_in[13];
  const float* g1Wih = (const float*)d_in[14];
  const float* g1Whh = (const float*)d_in[15];
  const float* g1bih = (const float*)d_in[16];
  const float* g1bhh = (const float*)d_in[17];
  const float* fcW   = (const float*)d_in[18];
  const float* fcb   = (const float*)d_in[19];
  float* out = (float*)d_out;

  // workspace layout (bytes); l0buf region is reused for GRU xw after rnn1
  char* ws = (char*)d_ws;
  u16*   l0buf = (u16*)(ws);                 // 33.6 MB (chunked) | xw 50.3 MB
  float* xwbuf = (float*)(ws);
  u16*   g0out = (u16*)(ws + 50331648);      // 8.39 MB
  u16*   g1out = (u16*)(ws + 58720256);      // 8.39 MB
  u16*   rnn1  = (u16*)(ws + 67108864);      // 8.39 MB
  int*   pre   = (int*)(ws + 75497472);      // 128 B

  const int CH = 4096;  // frames per rnn1 chunk
  for (int c = 0; c < NF_/CH; c++){
    l0_kernel<<<dim3(CH/4, 2), 512, 0, stream>>>(
        x + (size_t)c*CH*2048, r0Wih, r0Whh, r0bih, r0bhh, l0buf, CH);
    l1f_kernel<<<dim3(CH/4), 512, 0, stream>>>(
        l0buf, r1Wih, r1Whh, r1bih, r1bhh, rnn1 + (size_t)c*CH*256, CH);
    // layer1 backward @ s=15: tanh(u15 @ Wih_b^T + bih_b + bhh_b)
    gemm_bt<<<dim3(2, CH/64), 256, 0, stream>>>(
        l0buf + 15*256, 4096/2, r1Wih + 32768, 256,
        r1bih + 128, r1bhh + 128,
        (float*)nullptr, rnn1 + (size_t)c*CH*256 + 128, 256, 1);
  }
  // GRU layer 0
  gemm_bt<<<dim3(12, NF_/64), 256, 0, stream>>>(
      rnn1, 128, g0Wih, 256, g0bih, (const float*)nullptr,
      xwbuf, (u16*)nullptr, 768, 0);
  gru_scan<<<64, 384, 0, stream>>>(xwbuf, g0Whh, g0bhh, g0out);
  // GRU layer 1
  gemm_bt<<<dim3(12, NF_/64), 256, 0, stream>>>(
      g0out, 128, g1Wih, 256, g1bih, (const float*)nullptr,
      xwbuf, (u16*)nullptr, 768, 0);
  gru_scan<<<64, 384, 0, stream>>>(xwbuf, g1Whh, g1bhh, g1out);
  // FC + ragged scatter
  prefix_kernel<<<1, 64, 0, stream>>>(lens, pre);
  fc_kernel<<<NF_/64, 256, 0, stream>>>(g1out, fcW, fcb, lens, pre, out);
}

// Round 3
// 1332.470 us; speedup vs baseline: 3.9149x; 3.6282x over previous
//
#include <hip/hip_runtime.h>
#include <hip/hip_bf16.h>

#define B_ 32
#define T_ 512
#define L_ 16
#define F_ 128
#define H_ 128
#define C_ 61
#define NF_ (B_*T_)   // 16384 frames
#define CH_ 4096      // frames per rnn1 chunk

typedef unsigned int u32;
typedef unsigned short u16;
typedef __attribute__((ext_vector_type(8))) short s16x8;
typedef __attribute__((ext_vector_type(4))) float f32x4;

__device__ __forceinline__ float bflo(u32 v){ return __uint_as_float(v << 16); }
__device__ __forceinline__ float bfhi(u32 v){ return __uint_as_float(v & 0xffff0000u); }
__device__ __forceinline__ u16 f2bf(float f){
  u32 u = __float_as_uint(f);
  u += 0x7fffu + ((u >> 16) & 1u);
  return (u16)(u >> 16);
}
__device__ __forceinline__ u32 pack2(float a, float b){
  return (u32)f2bf(a) | ((u32)f2bf(b) << 16);
}
__device__ __forceinline__ float fast_tanh(float x){
  float e = __expf(2.f*x);
  return 1.f - 2.f/(e + 1.f);
}
__device__ __forceinline__ float fast_sigmoid(float x){
  return 1.f/(1.f + __expf(-x));
}
__device__ __forceinline__ f32x4 mfma16(s16x8 a, s16x8 b, f32x4 c){
  return __builtin_amdgcn_mfma_f32_16x16x32_bf16(a, b, c, 0, 0, 0);
}
// pack 8 consecutive f32 (two float4) into a bf16x8 fragment, k-order
__device__ __forceinline__ s16x8 packfrag(const float* p){
  const float4 a = *(const float4*)p;
  const float4 b = *(const float4*)(p+4);
  union { s16x8 v; u32 w[4]; } f;
  f.w[0]=pack2(a.x,a.y); f.w[1]=pack2(a.z,a.w);
  f.w[2]=pack2(b.x,b.y); f.w[3]=pack2(b.z,b.w);
  return f.v;
}

// ---------------------------------------------------------------------------
// rnn1 layer 0 via MFMA: WG = 32 frames x one dir, 256 thr (4 waves).
// Per step: acc = X_s@Wih^T + H@Whh^T (fused), tanh, H back to LDS.
// Wave w owns output-unit slice [32w,32w+32). Weights live in registers
// as B-fragments. H/X tiles in LDS padded to 136 u16 (272B rows).
// ---------------------------------------------------------------------------
__global__ __launch_bounds__(256) void l0_mfma(
    const float* __restrict__ x,      // (CH,16,128) chunk base
    const float* __restrict__ Wih,    // (2,128,128)
    const float* __restrict__ Whh,    // (2,128,128)
    const float* __restrict__ bih,    // (2,128)
    const float* __restrict__ bhh,    // (2,128)
    u16* __restrict__ out)            // (CH,16,256) bf16
{
  __shared__ __align__(16) u16 Hb[2][32][136];
  __shared__ __align__(16) u16 Xb[2][32][136];
  const int t = threadIdx.x;
  const int lane = t & 63, wv = t >> 6;
  const int l15 = lane & 15, kg = lane >> 4;
  const int dir = blockIdx.y;
  const int f0 = blockIdx.x * 32;
  // --- weight fragments (B-layout: row n = l15, k = 8*kg + e) ---
  s16x8 wih[2][4], whh[2][4];
  {
    const float* Wid = Wih + dir*16384;
    const float* Whd = Whh + dir*16384;
    #pragma unroll
    for (int nt = 0; nt < 2; nt++){
      const int u = wv*32 + nt*16 + l15;
      #pragma unroll
      for (int kc = 0; kc < 4; kc++){
        const int k = kc*32 + kg*8;
        wih[nt][kc] = packfrag(&Wid[u*128 + k]);
        whh[nt][kc] = packfrag(&Whd[u*128 + k]);
      }
    }
  }
  float bv[2];
  bv[0] = bih[dir*128 + wv*32 + l15]      + bhh[dir*128 + wv*32 + l15];
  bv[1] = bih[dir*128 + wv*32 + 16 + l15] + bhh[dir*128 + wv*32 + 16 + l15];
  // --- zero Hb[0], stage x(step 0) ---
  const int sr = t >> 3, sc = (t & 7) * 16;   // staging: row, col
  {
    *(uint4*)&Hb[0][sr][sc]   = make_uint4(0,0,0,0);
    *(uint4*)&Hb[0][sr][sc+8] = make_uint4(0,0,0,0);
    const int s0 = dir ? 15 : 0;
    const float4* xp = (const float4*)&x[(size_t)(f0+sr)*2048 + s0*128 + sc];
    const float4 v0 = xp[0], v1 = xp[1], v2 = xp[2], v3 = xp[3];
    *(uint4*)&Xb[0][sr][sc]   = make_uint4(pack2(v0.x,v0.y),pack2(v0.z,v0.w),
                                           pack2(v1.x,v1.y),pack2(v1.z,v1.w));
    *(uint4*)&Xb[0][sr][sc+8] = make_uint4(pack2(v2.x,v2.y),pack2(v2.z,v2.w),
                                           pack2(v3.x,v3.y),pack2(v3.z,v3.w));
  }
  __syncthreads();
  int cur = 0;
  for (int st = 0; st < 16; st++){
    const int s = dir ? (15-st) : st;
    float4 p0,p1,p2,p3;
    if (st < 15){
      const int sn = dir ? (14-st) : (st+1);
      const float4* xp = (const float4*)&x[(size_t)(f0+sr)*2048 + sn*128 + sc];
      p0 = xp[0]; p1 = xp[1]; p2 = xp[2]; p3 = xp[3];
    }
    f32x4 acc00 = {0.f,0.f,0.f,0.f}, acc01 = acc00, acc10 = acc00, acc11 = acc00;
    #pragma unroll
    for (int kc = 0; kc < 4; kc++){
      const int ko = kc*32 + kg*8;
      const s16x8 ax0 = *(const s16x8*)&Xb[cur][l15][ko];
      const s16x8 ax1 = *(const s16x8*)&Xb[cur][16+l15][ko];
      const s16x8 ah0 = *(const s16x8*)&Hb[cur][l15][ko];
      const s16x8 ah1 = *(const s16x8*)&Hb[cur][16+l15][ko];
      acc00 = mfma16(ax0, wih[0][kc], acc00);
      acc01 = mfma16(ax0, wih[1][kc], acc01);
      acc10 = mfma16(ax1, wih[0][kc], acc10);
      acc11 = mfma16(ax1, wih[1][kc], acc11);
      acc00 = mfma16(ah0, whh[0][kc], acc00);
      acc01 = mfma16(ah0, whh[1][kc], acc01);
      acc10 = mfma16(ah1, whh[0][kc], acc10);
      acc11 = mfma16(ah1, whh[1][kc], acc11);
    }
    // epilogue: D row=(kg*4+r) within m-tile, col=l15 within n-tile
    const int u0 = wv*32 + l15, u1 = wv*32 + 16 + l15;
    u16* op = out + (size_t)f0*4096 + s*256 + dir*128;
    #pragma unroll
    for (int r = 0; r < 4; r++){
      const int m0r = kg*4 + r, m1r = 16 + kg*4 + r;
      u16 h00 = f2bf(fast_tanh(acc00[r] + bv[0]));
      u16 h01 = f2bf(fast_tanh(acc01[r] + bv[1]));
      u16 h10 = f2bf(fast_tanh(acc10[r] + bv[0]));
      u16 h11 = f2bf(fast_tanh(acc11[r] + bv[1]));
      Hb[cur^1][m0r][u0] = h00;
      Hb[cur^1][m0r][u1] = h01;
      Hb[cur^1][m1r][u0] = h10;
      Hb[cur^1][m1r][u1] = h11;
      op[(size_t)m0r*4096 + u0] = h00;
      op[(size_t)m0r*4096 + u1] = h01;
      op[(size_t)m1r*4096 + u0] = h10;
      op[(size_t)m1r*4096 + u1] = h11;
    }
    if (st < 15){
      *(uint4*)&Xb[cur^1][sr][sc]   = make_uint4(pack2(p0.x,p0.y),pack2(p0.z,p0.w),
                                                 pack2(p1.x,p1.y),pack2(p1.z,p1.w));
      *(uint4*)&Xb[cur^1][sr][sc+8] = make_uint4(pack2(p2.x,p2.y),pack2(p2.z,p2.w),
                                                 pack2(p3.x,p3.y),pack2(p3.z,p3.w));
    }
    __syncthreads();
    cur ^= 1;
  }
}

// ---------------------------------------------------------------------------
// rnn1 layer 1 FORWARD via MFMA. Input U = l0 out (CH,16,256) bf16, K_in=256.
// Same structure as l0_mfma; only h at s=15 is written out.
// ---------------------------------------------------------------------------
__global__ __launch_bounds__(256) void l1f_mfma(
    const u16* __restrict__ U,        // (CH,16,256) bf16
    const float* __restrict__ Wih,    // (2,128,256) dir0
    const float* __restrict__ Whh,    // (2,128,128) dir0
    const float* __restrict__ bih,    // (2,128)
    const float* __restrict__ bhh,
    u16* __restrict__ out)            // rnn1 rows (ld 256), cols 0..127
{
  __shared__ __align__(16) u16 Hb[2][32][136];
  __shared__ __align__(16) u16 Xb[2][32][264];
  const int t = threadIdx.x;
  const int lane = t & 63, wv = t >> 6;
  const int l15 = lane & 15, kg = lane >> 4;
  const int f0 = blockIdx.x * 32;
  s16x8 wih[2][8], whh[2][4];
  {
    #pragma unroll
    for (int nt = 0; nt < 2; nt++){
      const int u = wv*32 + nt*16 + l15;
      #pragma unroll
      for (int kc = 0; kc < 8; kc++)
        wih[nt][kc] = packfrag(&Wih[u*256 + kc*32 + kg*8]);
      #pragma unroll
      for (int kc = 0; kc < 4; kc++)
        whh[nt][kc] = packfrag(&Whh[u*128 + kc*32 + kg*8]);
    }
  }
  float bv[2];
  bv[0] = bih[wv*32 + l15]      + bhh[wv*32 + l15];
  bv[1] = bih[wv*32 + 16 + l15] + bhh[wv*32 + 16 + l15];
  const int sr = t >> 3, sc = (t & 7) * 32;   // staging: row, u16-col (64B/thr)
  {
    *(uint4*)&Hb[0][sr][(t&7)*16]   = make_uint4(0,0,0,0);
    *(uint4*)&Hb[0][sr][(t&7)*16+8] = make_uint4(0,0,0,0);
    const uint4* up = (const uint4*)&U[(size_t)(f0+sr)*4096 + 0*256 + sc];
    uint4 c0 = up[0], c1 = up[1], c2 = up[2], c3 = up[3];
    *(uint4*)&Xb[0][sr][sc]    = c0;
    *(uint4*)&Xb[0][sr][sc+8]  = c1;
    *(uint4*)&Xb[0][sr][sc+16] = c2;
    *(uint4*)&Xb[0][sr][sc+24] = c3;
  }
  __syncthreads();
  int cur = 0;
  for (int st = 0; st < 16; st++){
    uint4 c0,c1,c2,c3;
    if (st < 15){
      const uint4* up = (const uint4*)&U[(size_t)(f0+sr)*4096 + (st+1)*256 + sc];
      c0 = up[0]; c1 = up[1]; c2 = up[2]; c3 = up[3];
    }
    f32x4 acc00 = {0.f,0.f,0.f,0.f}, acc01 = acc00, acc10 = acc00, acc11 = acc00;
    #pragma unroll
    for (int kc = 0; kc < 8; kc++){
      const int ko = kc*32 + kg*8;
      const s16x8 ax0 = *(const s16x8*)&Xb[cur][l15][ko];
      const s16x8 ax1 = *(const s16x8*)&Xb[cur][16+l15][ko];
      acc00 = mfma16(ax0, wih[0][kc], acc00);
      acc01 = mfma16(ax0, wih[1][kc], acc01);
      acc10 = mfma16(ax1, wih[0][kc], acc10);
      acc11 = mfma16(ax1, wih[1][kc], acc11);
    }
    #pragma unroll
    for (int kc = 0; kc < 4; kc++){
      const int ko = kc*32 + kg*8;
      const s16x8 ah0 = *(const s16x8*)&Hb[cur][l15][ko];
      const s16x8 ah1 = *(const s16x8*)&Hb[cur][16+l15][ko];
      acc00 = mfma16(ah0, whh[0][kc], acc00);
      acc01 = mfma16(ah0, whh[1][kc], acc01);
      acc10 = mfma16(ah1, whh[0][kc], acc10);
      acc11 = mfma16(ah1, whh[1][kc], acc11);
    }
    const int u0 = wv*32 + l15, u1 = wv*32 + 16 + l15;
    #pragma unroll
    for (int r = 0; r < 4; r++){
      const int m0r = kg*4 + r, m1r = 16 + kg*4 + r;
      const u16 h00 = f2bf(fast_tanh(acc00[r] + bv[0]));
      const u16 h01 = f2bf(fast_tanh(acc01[r] + bv[1]));
      const u16 h10 = f2bf(fast_tanh(acc10[r] + bv[0]));
      const u16 h11 = f2bf(fast_tanh(acc11[r] + bv[1]));
      Hb[cur^1][m0r][u0] = h00;
      Hb[cur^1][m0r][u1] = h01;
      Hb[cur^1][m1r][u0] = h10;
      Hb[cur^1][m1r][u1] = h11;
      if (st == 15){
        out[(size_t)(f0+m0r)*256 + u0] = h00;
        out[(size_t)(f0+m0r)*256 + u1] = h01;
        out[(size_t)(f0+m1r)*256 + u0] = h10;
        out[(size_t)(f0+m1r)*256 + u1] = h11;
      }
    }
    if (st < 15){
      *(uint4*)&Xb[cur^1][sr][sc]    = c0;
      *(uint4*)&Xb[cur^1][sr][sc+8]  = c1;
      *(uint4*)&Xb[cur^1][sr][sc+16] = c2;
      *(uint4*)&Xb[cur^1][sr][sc+24] = c3;
    }
    __syncthreads();
    cur ^= 1;
  }
}

// ---------------------------------------------------------------------------
// Register-only MFMA GEMM: C(M,N) = A(bf16 M,K; lda) @ Wb(bf16 N,K)^T + bias
// [tanh], out fp32 (Cf,ldc) or bf16 (Cb,ldc). WG: 4 waves, tile M=64,N=32;
// wave w does rows [m0+16w, +16). A/B fragments straight from global.
// ---------------------------------------------------------------------------
__global__ __launch_bounds__(256) void mfma_gemm(
    const u16* __restrict__ A, int lda,
    const u16* __restrict__ Wb, int K,
    const float* __restrict__ bias,
    float* __restrict__ Cf, u16* __restrict__ Cb, int ldc, int act)
{
  const int t = threadIdx.x;
  const int lane = t & 63, wv = t >> 6;
  const int l15 = lane & 15, kg = lane >> 4;
  const int n0 = blockIdx.x * 32;
  const int m0 = blockIdx.y * 64 + wv*16;
  const u16* Ap = A + (size_t)(m0 + l15)*lda + kg*8;
  const u16* W0 = Wb + (size_t)(n0 + l15)*K + kg*8;
  const u16* W1 = Wb + (size_t)(n0 + 16 + l15)*K + kg*8;
  f32x4 acc0 = {0.f,0.f,0.f,0.f}, acc1 = acc0;
  #pragma unroll 4
  for (int kc = 0; kc < K/32; kc++){
    const s16x8 a  = *(const s16x8*)(Ap + kc*32);
    const s16x8 b0 = *(const s16x8*)(W0 + kc*32);
    const s16x8 b1 = *(const s16x8*)(W1 + kc*32);
    acc0 = mfma16(a, b0, acc0);
    acc1 = mfma16(a, b1, acc1);
  }
  const int col0 = n0 + l15, col1 = n0 + 16 + l15;
  const float bv0 = bias[col0], bv1 = bias[col1];
  #pragma unroll
  for (int r = 0; r < 4; r++){
    const int row = m0 + kg*4 + r;
    float v0 = acc0[r] + bv0, v1 = acc1[r] + bv1;
    if (act){ v0 = fast_tanh(v0); v1 = fast_tanh(v1); }
    if (Cf){
      Cf[(size_t)row*ldc + col0] = v0;
      Cf[(size_t)row*ldc + col1] = v1;
    } else {
      Cb[(size_t)row*ldc + col0] = f2bf(v0);
      Cb[(size_t)row*ldc + col1] = f2bf(v1);
    }
  }
}

// ---------------------------------------------------------------------------
// Weight prep: fp32 -> bf16 copies + fused l1-backward bias.
// ---------------------------------------------------------------------------
__global__ __launch_bounds__(256) void prep_kernel(
    const float* __restrict__ g0W, const float* __restrict__ g1W,
    const float* __restrict__ r1Wih,
    const float* __restrict__ r1bih, const float* __restrict__ r1bhh,
    u16* __restrict__ g0o, u16* __restrict__ g1o, u16* __restrict__ r1o,
    float* __restrict__ bo)
{
  const int i = blockIdx.x*256 + threadIdx.x;
  if (i < 196608){ g0o[i] = f2bf(g0W[i]); g1o[i] = f2bf(g1W[i]); }
  if (i < 32768)   r1o[i] = f2bf(r1Wih[32768 + i]);
  if (i < 128)     bo[i]  = r1bih[128+i] + r1bhh[128+i];
}

// ---------------------------------------------------------------------------
// GRU recurrence (unchanged from round 2): Whh in registers, xw prefetched
// 2 steps ahead from global, h in LDS.
// ---------------------------------------------------------------------------
__global__ __launch_bounds__(384) void gru_scan(
    const float* __restrict__ xw,   // (16384,768)
    const float* __restrict__ Whh,  // (2,384,128)
    const float* __restrict__ bhh,  // (2,384)
    u16* __restrict__ hout)         // (16384,256) bf16
{
  __shared__ __align__(16) float h[128];
  __shared__ float gl[384];
  const int t = threadIdx.x;
  const int b = blockIdx.x >> 1, dir = blockIdx.x & 1;
  uint2 wreg[32];
  {
    const float* Wd = Whh + (size_t)dir*49152 + (size_t)t*128;
    #pragma unroll
    for (int k4 = 0; k4 < 32; k4++){
      const float4 w = *(const float4*)&Wd[k4*4];
      wreg[k4] = make_uint2(pack2(w.x, w.y), pack2(w.z, w.w));
    }
  }
  const float bh = bhh[dir*384 + t];
  const float* xwb = xw + (size_t)b*512*768 + dir*384;
  float hreg = 0.f;
  float pxr0=0,pxz0=0,pxn0=0, pxr1=0,pxz1=0,pxn1=0;
  if (t < 128){
    h[t] = 0.f;
    const int t0 = dir ? 511 : 0;
    const int t1 = dir ? 510 : 1;
    pxr0 = xwb[(size_t)t0*768 + t];
    pxz0 = xwb[(size_t)t0*768 + 128 + t];
    pxn0 = xwb[(size_t)t0*768 + 256 + t];
    pxr1 = xwb[(size_t)t1*768 + t];
    pxz1 = xwb[(size_t)t1*768 + 128 + t];
    pxn1 = xwb[(size_t)t1*768 + 256 + t];
  }
  __syncthreads();

#define GRU_STEP(TI, PR, PZ, PN)                                            \
  {                                                                         \
    const int tt = dir ? (511 - (TI)) : (TI);                               \
    float s0=0,s1=0,s2=0,s3=0;                                              \
    const float4* hp = (const float4*)h;                                    \
    _Pragma("unroll")                                                       \
    for (int k4 = 0; k4 < 32; k4++){                                        \
      const uint2 wp = wreg[k4];                                            \
      const float4 hv = hp[k4];                                             \
      s0 = fmaf(bflo(wp.x), hv.x, s0);                                      \
      s1 = fmaf(bfhi(wp.x), hv.y, s1);                                      \
      s2 = fmaf(bflo(wp.y), hv.z, s2);                                      \
      s3 = fmaf(bfhi(wp.y), hv.w, s3);                                      \
    }                                                                       \
    gl[t] = bh + s0+s1+s2+s3;                                               \
    __syncthreads();                                                        \
    if (t < 128){                                                           \
      const float r = fast_sigmoid(PR + gl[t]);                             \
      const float z = fast_sigmoid(PZ + gl[128+t]);                         \
      const float n = fast_tanh(PN + r*gl[256+t]);                          \
      const float hn = (1.f - z)*n + z*hreg;                                \
      hreg = hn;                                                            \
      h[t] = hn;                                                            \
      hout[((size_t)b*512 + tt)*256 + dir*128 + t] = f2bf(hn);              \
      int tn = dir ? (511 - ((TI)+2)) : ((TI)+2);                           \
      tn = tn < 0 ? 0 : (tn > 511 ? 511 : tn);                              \
      const float* xp = xwb + (size_t)tn*768;                               \
      PR = xp[t]; PZ = xp[128+t]; PN = xp[256+t];                           \
    }                                                                       \
    __syncthreads();                                                        \
  }

  for (int ti = 0; ti < 512; ti += 2){
    GRU_STEP(ti,   pxr0, pxz0, pxn0);
    GRU_STEP(ti+1, pxr1, pxz1, pxn1);
  }
#undef GRU_STEP
}

__global__ void prefix_kernel(const int* __restrict__ lengths, int* __restrict__ pre){
  if (threadIdx.x == 0 && blockIdx.x == 0){
    int run = 0;
    for (int b = 0; b < 32; b++){ pre[b] = run; run += lengths[b]; }
  }
}

// ---------------------------------------------------------------------------
// Final FC (61 x 256) + ragged masked scatter into d_out (unchanged).
// ---------------------------------------------------------------------------
__global__ __launch_bounds__(256) void fc_kernel(
    const u16* __restrict__ A,      // (16384,256) bf16
    const float* __restrict__ W,    // (61,256)
    const float* __restrict__ bias, // (61)
    const int* __restrict__ lengths,
    const int* __restrict__ pre,
    float* __restrict__ out)
{
  __shared__ __align__(16) float4 Wl[64][61];
  __shared__ __align__(16) float  Al[64][256];
  const int t = threadIdx.x;
  const int row0 = blockIdx.x * 64;
  for (int idx = t; idx < 61*64; idx += 256){
    int c = idx >> 6, k4 = idx & 63;
    Wl[k4][c] = *(const float4*)&W[(size_t)c*256 + k4*4];
  }
  {
    const u32* A32 = (const u32*)(A + (size_t)row0*256);
    for (int idx = t; idx < 8192; idx += 256){
      u32 v = A32[idx];
      int r = idx >> 7, kp = idx & 127;
      Al[r][2*kp]   = bflo(v);
      Al[r][2*kp+1] = bfhi(v);
    }
  }
  __syncthreads();
  const int c = t & 63;
  const int rbase = t >> 6;
  if (c < 61){
    const float bv = bias[c];
    for (int rr = rbase; rr < 64; rr += 4){
      float s0=0,s1=0,s2=0,s3=0;
      const float4* Ap = (const float4*)&Al[rr][0];
      #pragma unroll
      for (int k4 = 0; k4 < 64; k4++){
        const float4 w = Wl[k4][c];
        const float4 a = Ap[k4];
        s0 = fmaf(w.x, a.x, s0);
        s1 = fmaf(w.y, a.y, s1);
        s2 = fmaf(w.z, a.z, s2);
        s3 = fmaf(w.w, a.w, s3);
      }
      const int n = row0 + rr;
      const int b = n >> 9, tt = n & 511;
      if (tt < lengths[b])
        out[(size_t)(pre[b] + tt)*61 + c] = bv + s0+s1+s2+s3;
    }
  }
}

extern "C" void kernel_launch(void* const* d_in, const int* in_sizes, int n_in,
                              void* d_out, int out_size, void* d_ws, size_t ws_size,
                              hipStream_t stream)
{
  const float* x     = (const float*)d_in[0];
  const int*   lens  = (const int*)d_in[1];
  const float* r0Wih = (const float*)d_in[2];
  const float* r0Whh = (const float*)d_in[3];
  const float* r0bih = (const float*)d_in[4];
  const float* r0bhh = (const float*)d_in[5];
  const float* r1Wih = (const float*)d_in[6];
  const float* r1Whh = (const float*)d_in[7];
  const float* r1bih = (const float*)d_in[8];
  const float* r1bhh = (const float*)d_in[9];
  const float* g0Wih = (const float*)d_in[10];
  const float* g0Whh = (const float*)d_in[11];
  const float* g0bih = (const float*)d_in[12];
  const float* g0bhh = (const float*)d_in[13];
  const float* g1Wih = (const float*)d_in[14];
  const float* g1Whh = (const float*)d_in[15];
  const float* g1bih = (const float*)d_in[16];
  const float* g1bhh = (const float*)d_in[17];
  const float* fcW   = (const float*)d_in[18];
  const float* fcb   = (const float*)d_in[19];
  float* out = (float*)d_out;

  // workspace layout (bytes), total 75497600 (same footprint as round 2):
  // [0, 50.3MB): xw fp32; first 33.55MB doubles as l0buf during rnn1 phase
  // [48MB): g0out ; [56MB): g1out (early: bf16 weight prep area) ; [64MB): rnn1
  char* ws = (char*)d_ws;
  u16*   l0buf = (u16*)(ws);
  float* xwbuf = (float*)(ws);
  u16*   g0out = (u16*)(ws + 50331648);
  u16*   g0Wb  = (u16*)(ws + 58720256);             // 393216 B
  u16*   g1Wb  = (u16*)(ws + 58720256 + 393216);    // 393216 B
  u16*   r1Wb  = (u16*)(ws + 58720256 + 786432);    // 65536 B
  float* biasb = (float*)(ws + 58720256 + 851968);  // 512 B
  u16*   g1out = (u16*)(ws + 58720256);             // overwrites prep late
  u16*   rnn1  = (u16*)(ws + 67108864);
  int*   pre   = (int*)(ws + 75497472);

  prep_kernel<<<768, 256, 0, stream>>>(g0Wih, g1Wih, r1Wih, r1bih, r1bhh,
                                       g0Wb, g1Wb, r1Wb, biasb);
  for (int c = 0; c < NF_/CH_; c++){
    l0_mfma<<<dim3(CH_/32, 2), 256, 0, stream>>>(
        x + (size_t)c*CH_*2048, r0Wih, r0Whh, r0bih, r0bhh, l0buf);
    l1f_mfma<<<dim3(CH_/32), 256, 0, stream>>>(
        l0buf, r1Wih, r1Whh, r1bih, r1bhh, rnn1 + (size_t)c*CH_*256);
    // layer1 backward @ s=15: tanh(u15 @ Wih_b^T + bih_b + bhh_b)
    mfma_gemm<<<dim3(128/32, CH_/64), 256, 0, stream>>>(
        l0buf + 15*256, 4096, r1Wb, 256, biasb,
        (float*)nullptr, rnn1 + (size_t)c*CH_*256 + 128, 256, 1);
  }
  // GRU layer 0
  mfma_gemm<<<dim3(768/32, NF_/64), 256, 0, stream>>>(
      rnn1, 256, g0Wb, 256, g0bih, xwbuf, (u16*)nullptr, 768, 0);
  gru_scan<<<64, 384, 0, stream>>>(xwbuf, g0Whh, g0bhh, g0out);
  // GRU layer 1
  mfma_gemm<<<dim3(768/32, NF_/64), 256, 0, stream>>>(
      g0out, 256, g1Wb, 256, g1bih, xwbuf, (u16*)nullptr, 768, 0);
  gru_scan<<<64, 384, 0, stream>>>(xwbuf, g1Whh, g1bhh, g1out);
  // FC + ragged scatter
  prefix_kernel<<<1, 64, 0, stream>>>(lens, pre);
  fc_kernel<<<NF_/64, 256, 0, stream>>>(g1out, fcW, fcb, lens, pre, out);
}

// Round 4
// 1183.753 us; speedup vs baseline: 4.4068x; 1.1256x over previous
//
#include <hip/hip_runtime.h>
#include <hip/hip_bf16.h>

#define B_ 32
#define T_ 512
#define L_ 16
#define F_ 128
#define H_ 128
#define C_ 61
#define NF_ (B_*T_)   // 16384 frames
#define CH_ 4096      // frames per rnn1 chunk

typedef unsigned int u32;
typedef unsigned short u16;
typedef __attribute__((ext_vector_type(8))) short s16x8;
typedef __attribute__((ext_vector_type(4))) float f32x4;

__device__ __forceinline__ float bflo(u32 v){ return __uint_as_float(v << 16); }
__device__ __forceinline__ float bfhi(u32 v){ return __uint_as_float(v & 0xffff0000u); }
__device__ __forceinline__ u16 f2bf(float f){
  u32 u = __float_as_uint(f);
  u += 0x7fffu + ((u >> 16) & 1u);
  return (u16)(u >> 16);
}
__device__ __forceinline__ u32 pack2(float a, float b){
  return (u32)f2bf(a) | ((u32)f2bf(b) << 16);
}
__device__ __forceinline__ float fast_tanh(float x){
  float e = __expf(2.f*x);
  return 1.f - 2.f*__builtin_amdgcn_rcpf(e + 1.f);
}
__device__ __forceinline__ float fast_sigmoid(float x){
  return __builtin_amdgcn_rcpf(1.f + __expf(-x));
}
__device__ __forceinline__ f32x4 mfma16(s16x8 a, s16x8 b, f32x4 c){
  return __builtin_amdgcn_mfma_f32_16x16x32_bf16(a, b, c, 0, 0, 0);
}
// pack 8 consecutive f32 (two float4) into a bf16x8 fragment, k-order
__device__ __forceinline__ s16x8 packfrag(const float* p){
  const float4 a = *(const float4*)p;
  const float4 b = *(const float4*)(p+4);
  union { s16x8 v; u32 w[4]; } f;
  f.w[0]=pack2(a.x,a.y); f.w[1]=pack2(a.z,a.w);
  f.w[2]=pack2(b.x,b.y); f.w[3]=pack2(b.z,b.w);
  return f.v;
}

// ---------------------------------------------------------------------------
// rnn1 layer 0 via MFMA (unchanged from round 3)
// ---------------------------------------------------------------------------
__global__ __launch_bounds__(256) void l0_mfma(
    const float* __restrict__ x,      // (CH,16,128) chunk base
    const float* __restrict__ Wih,    // (2,128,128)
    const float* __restrict__ Whh,    // (2,128,128)
    const float* __restrict__ bih,    // (2,128)
    const float* __restrict__ bhh,    // (2,128)
    u16* __restrict__ out)            // (CH,16,256) bf16
{
  __shared__ __align__(16) u16 Hb[2][32][136];
  __shared__ __align__(16) u16 Xb[2][32][136];
  const int t = threadIdx.x;
  const int lane = t & 63, wv = t >> 6;
  const int l15 = lane & 15, kg = lane >> 4;
  const int dir = blockIdx.y;
  const int f0 = blockIdx.x * 32;
  s16x8 wih[2][4], whh[2][4];
  {
    const float* Wid = Wih + dir*16384;
    const float* Whd = Whh + dir*16384;
    #pragma unroll
    for (int nt = 0; nt < 2; nt++){
      const int u = wv*32 + nt*16 + l15;
      #pragma unroll
      for (int kc = 0; kc < 4; kc++){
        const int k = kc*32 + kg*8;
        wih[nt][kc] = packfrag(&Wid[u*128 + k]);
        whh[nt][kc] = packfrag(&Whd[u*128 + k]);
      }
    }
  }
  float bv[2];
  bv[0] = bih[dir*128 + wv*32 + l15]      + bhh[dir*128 + wv*32 + l15];
  bv[1] = bih[dir*128 + wv*32 + 16 + l15] + bhh[dir*128 + wv*32 + 16 + l15];
  const int sr = t >> 3, sc = (t & 7) * 16;
  {
    *(uint4*)&Hb[0][sr][sc]   = make_uint4(0,0,0,0);
    *(uint4*)&Hb[0][sr][sc+8] = make_uint4(0,0,0,0);
    const int s0 = dir ? 15 : 0;
    const float4* xp = (const float4*)&x[(size_t)(f0+sr)*2048 + s0*128 + sc];
    const float4 v0 = xp[0], v1 = xp[1], v2 = xp[2], v3 = xp[3];
    *(uint4*)&Xb[0][sr][sc]   = make_uint4(pack2(v0.x,v0.y),pack2(v0.z,v0.w),
                                           pack2(v1.x,v1.y),pack2(v1.z,v1.w));
    *(uint4*)&Xb[0][sr][sc+8] = make_uint4(pack2(v2.x,v2.y),pack2(v2.z,v2.w),
                                           pack2(v3.x,v3.y),pack2(v3.z,v3.w));
  }
  __syncthreads();
  int cur = 0;
  for (int st = 0; st < 16; st++){
    const int s = dir ? (15-st) : st;
    float4 p0,p1,p2,p3;
    if (st < 15){
      const int sn = dir ? (14-st) : (st+1);
      const float4* xp = (const float4*)&x[(size_t)(f0+sr)*2048 + sn*128 + sc];
      p0 = xp[0]; p1 = xp[1]; p2 = xp[2]; p3 = xp[3];
    }
    f32x4 acc00 = {0.f,0.f,0.f,0.f}, acc01 = acc00, acc10 = acc00, acc11 = acc00;
    #pragma unroll
    for (int kc = 0; kc < 4; kc++){
      const int ko = kc*32 + kg*8;
      const s16x8 ax0 = *(const s16x8*)&Xb[cur][l15][ko];
      const s16x8 ax1 = *(const s16x8*)&Xb[cur][16+l15][ko];
      const s16x8 ah0 = *(const s16x8*)&Hb[cur][l15][ko];
      const s16x8 ah1 = *(const s16x8*)&Hb[cur][16+l15][ko];
      acc00 = mfma16(ax0, wih[0][kc], acc00);
      acc01 = mfma16(ax0, wih[1][kc], acc01);
      acc10 = mfma16(ax1, wih[0][kc], acc10);
      acc11 = mfma16(ax1, wih[1][kc], acc11);
      acc00 = mfma16(ah0, whh[0][kc], acc00);
      acc01 = mfma16(ah0, whh[1][kc], acc01);
      acc10 = mfma16(ah1, whh[0][kc], acc10);
      acc11 = mfma16(ah1, whh[1][kc], acc11);
    }
    const int u0 = wv*32 + l15, u1 = wv*32 + 16 + l15;
    u16* op = out + (size_t)f0*4096 + s*256 + dir*128;
    #pragma unroll
    for (int r = 0; r < 4; r++){
      const int m0r = kg*4 + r, m1r = 16 + kg*4 + r;
      u16 h00 = f2bf(fast_tanh(acc00[r] + bv[0]));
      u16 h01 = f2bf(fast_tanh(acc01[r] + bv[1]));
      u16 h10 = f2bf(fast_tanh(acc10[r] + bv[0]));
      u16 h11 = f2bf(fast_tanh(acc11[r] + bv[1]));
      Hb[cur^1][m0r][u0] = h00;
      Hb[cur^1][m0r][u1] = h01;
      Hb[cur^1][m1r][u0] = h10;
      Hb[cur^1][m1r][u1] = h11;
      op[(size_t)m0r*4096 + u0] = h00;
      op[(size_t)m0r*4096 + u1] = h01;
      op[(size_t)m1r*4096 + u0] = h10;
      op[(size_t)m1r*4096 + u1] = h11;
    }
    if (st < 15){
      *(uint4*)&Xb[cur^1][sr][sc]   = make_uint4(pack2(p0.x,p0.y),pack2(p0.z,p0.w),
                                                 pack2(p1.x,p1.y),pack2(p1.z,p1.w));
      *(uint4*)&Xb[cur^1][sr][sc+8] = make_uint4(pack2(p2.x,p2.y),pack2(p2.z,p2.w),
                                                 pack2(p3.x,p3.y),pack2(p3.z,p3.w));
    }
    __syncthreads();
    cur ^= 1;
  }
}

// ---------------------------------------------------------------------------
// rnn1 layer 1 FORWARD via MFMA (unchanged from round 3)
// ---------------------------------------------------------------------------
__global__ __launch_bounds__(256) void l1f_mfma(
    const u16* __restrict__ U,        // (CH,16,256) bf16
    const float* __restrict__ Wih,    // (2,128,256) dir0
    const float* __restrict__ Whh,    // (2,128,128) dir0
    const float* __restrict__ bih,    // (2,128)
    const float* __restrict__ bhh,
    u16* __restrict__ out)            // rnn1 rows (ld 256), cols 0..127
{
  __shared__ __align__(16) u16 Hb[2][32][136];
  __shared__ __align__(16) u16 Xb[2][32][264];
  const int t = threadIdx.x;
  const int lane = t & 63, wv = t >> 6;
  const int l15 = lane & 15, kg = lane >> 4;
  const int f0 = blockIdx.x * 32;
  s16x8 wih[2][8], whh[2][4];
  {
    #pragma unroll
    for (int nt = 0; nt < 2; nt++){
      const int u = wv*32 + nt*16 + l15;
      #pragma unroll
      for (int kc = 0; kc < 8; kc++)
        wih[nt][kc] = packfrag(&Wih[u*256 + kc*32 + kg*8]);
      #pragma unroll
      for (int kc = 0; kc < 4; kc++)
        whh[nt][kc] = packfrag(&Whh[u*128 + kc*32 + kg*8]);
    }
  }
  float bv[2];
  bv[0] = bih[wv*32 + l15]      + bhh[wv*32 + l15];
  bv[1] = bih[wv*32 + 16 + l15] + bhh[wv*32 + 16 + l15];
  const int sr = t >> 3, sc = (t & 7) * 32;
  {
    *(uint4*)&Hb[0][sr][(t&7)*16]   = make_uint4(0,0,0,0);
    *(uint4*)&Hb[0][sr][(t&7)*16+8] = make_uint4(0,0,0,0);
    const uint4* up = (const uint4*)&U[(size_t)(f0+sr)*4096 + 0*256 + sc];
    uint4 c0 = up[0], c1 = up[1], c2 = up[2], c3 = up[3];
    *(uint4*)&Xb[0][sr][sc]    = c0;
    *(uint4*)&Xb[0][sr][sc+8]  = c1;
    *(uint4*)&Xb[0][sr][sc+16] = c2;
    *(uint4*)&Xb[0][sr][sc+24] = c3;
  }
  __syncthreads();
  int cur = 0;
  for (int st = 0; st < 16; st++){
    uint4 c0,c1,c2,c3;
    if (st < 15){
      const uint4* up = (const uint4*)&U[(size_t)(f0+sr)*4096 + (st+1)*256 + sc];
      c0 = up[0]; c1 = up[1]; c2 = up[2]; c3 = up[3];
    }
    f32x4 acc00 = {0.f,0.f,0.f,0.f}, acc01 = acc00, acc10 = acc00, acc11 = acc00;
    #pragma unroll
    for (int kc = 0; kc < 8; kc++){
      const int ko = kc*32 + kg*8;
      const s16x8 ax0 = *(const s16x8*)&Xb[cur][l15][ko];
      const s16x8 ax1 = *(const s16x8*)&Xb[cur][16+l15][ko];
      acc00 = mfma16(ax0, wih[0][kc], acc00);
      acc01 = mfma16(ax0, wih[1][kc], acc01);
      acc10 = mfma16(ax1, wih[0][kc], acc10);
      acc11 = mfma16(ax1, wih[1][kc], acc11);
    }
    #pragma unroll
    for (int kc = 0; kc < 4; kc++){
      const int ko = kc*32 + kg*8;
      const s16x8 ah0 = *(const s16x8*)&Hb[cur][l15][ko];
      const s16x8 ah1 = *(const s16x8*)&Hb[cur][16+l15][ko];
      acc00 = mfma16(ah0, whh[0][kc], acc00);
      acc01 = mfma16(ah0, whh[1][kc], acc01);
      acc10 = mfma16(ah1, whh[0][kc], acc10);
      acc11 = mfma16(ah1, whh[1][kc], acc11);
    }
    const int u0 = wv*32 + l15, u1 = wv*32 + 16 + l15;
    #pragma unroll
    for (int r = 0; r < 4; r++){
      const int m0r = kg*4 + r, m1r = 16 + kg*4 + r;
      const u16 h00 = f2bf(fast_tanh(acc00[r] + bv[0]));
      const u16 h01 = f2bf(fast_tanh(acc01[r] + bv[1]));
      const u16 h10 = f2bf(fast_tanh(acc10[r] + bv[0]));
      const u16 h11 = f2bf(fast_tanh(acc11[r] + bv[1]));
      Hb[cur^1][m0r][u0] = h00;
      Hb[cur^1][m0r][u1] = h01;
      Hb[cur^1][m1r][u0] = h10;
      Hb[cur^1][m1r][u1] = h11;
      if (st == 15){
        out[(size_t)(f0+m0r)*256 + u0] = h00;
        out[(size_t)(f0+m0r)*256 + u1] = h01;
        out[(size_t)(f0+m1r)*256 + u0] = h10;
        out[(size_t)(f0+m1r)*256 + u1] = h11;
      }
    }
    if (st < 15){
      *(uint4*)&Xb[cur^1][sr][sc]    = c0;
      *(uint4*)&Xb[cur^1][sr][sc+8]  = c1;
      *(uint4*)&Xb[cur^1][sr][sc+16] = c2;
      *(uint4*)&Xb[cur^1][sr][sc+24] = c3;
    }
    __syncthreads();
    cur ^= 1;
  }
}

// ---------------------------------------------------------------------------
// Register-only MFMA GEMM: C(M,N) = A @ Wb^T + bias [tanh], bf16/f32 out.
// ---------------------------------------------------------------------------
__global__ __launch_bounds__(256) void mfma_gemm(
    const u16* __restrict__ A, int lda,
    const u16* __restrict__ Wb, int K,
    const float* __restrict__ bias,
    float* __restrict__ Cf, u16* __restrict__ Cb, int ldc, int act)
{
  const int t = threadIdx.x;
  const int lane = t & 63, wv = t >> 6;
  const int l15 = lane & 15, kg = lane >> 4;
  const int n0 = blockIdx.x * 32;
  const int m0 = blockIdx.y * 64 + wv*16;
  const u16* Ap = A + (size_t)(m0 + l15)*lda + kg*8;
  const u16* W0 = Wb + (size_t)(n0 + l15)*K + kg*8;
  const u16* W1 = Wb + (size_t)(n0 + 16 + l15)*K + kg*8;
  f32x4 acc0 = {0.f,0.f,0.f,0.f}, acc1 = acc0;
  #pragma unroll 4
  for (int kc = 0; kc < K/32; kc++){
    const s16x8 a  = *(const s16x8*)(Ap + kc*32);
    const s16x8 b0 = *(const s16x8*)(W0 + kc*32);
    const s16x8 b1 = *(const s16x8*)(W1 + kc*32);
    acc0 = mfma16(a, b0, acc0);
    acc1 = mfma16(a, b1, acc1);
  }
  const int col0 = n0 + l15, col1 = n0 + 16 + l15;
  const float bv0 = bias[col0], bv1 = bias[col1];
  #pragma unroll
  for (int r = 0; r < 4; r++){
    const int row = m0 + kg*4 + r;
    float v0 = acc0[r] + bv0, v1 = acc1[r] + bv1;
    if (act){ v0 = fast_tanh(v0); v1 = fast_tanh(v1); }
    if (Cf){
      Cf[(size_t)row*ldc + col0] = v0;
      Cf[(size_t)row*ldc + col1] = v1;
    } else {
      Cb[(size_t)row*ldc + col0] = f2bf(v0);
      Cb[(size_t)row*ldc + col1] = f2bf(v1);
    }
  }
}

// ---------------------------------------------------------------------------
// xw GEMM: same compute as mfma_gemm, but stores into transposed layout
// xwT[dir][tt][b][384]  (row = frame = b*512+tt, col in [0,768) = dir*384+c)
// ---------------------------------------------------------------------------
__global__ __launch_bounds__(256) void gemm_xw(
    const u16* __restrict__ A, int lda,
    const u16* __restrict__ Wb, int K,
    const float* __restrict__ bias,
    float* __restrict__ xwT)
{
  const int t = threadIdx.x;
  const int lane = t & 63, wv = t >> 6;
  const int l15 = lane & 15, kg = lane >> 4;
  const int n0 = blockIdx.x * 32;
  const int m0 = blockIdx.y * 64 + wv*16;
  const u16* Ap = A + (size_t)(m0 + l15)*lda + kg*8;
  const u16* W0 = Wb + (size_t)(n0 + l15)*K + kg*8;
  const u16* W1 = Wb + (size_t)(n0 + 16 + l15)*K + kg*8;
  f32x4 acc0 = {0.f,0.f,0.f,0.f}, acc1 = acc0;
  #pragma unroll 4
  for (int kc = 0; kc < K/32; kc++){
    const s16x8 a  = *(const s16x8*)(Ap + kc*32);
    const s16x8 b0 = *(const s16x8*)(W0 + kc*32);
    const s16x8 b1 = *(const s16x8*)(W1 + kc*32);
    acc0 = mfma16(a, b0, acc0);
    acc1 = mfma16(a, b1, acc1);
  }
  const int col0 = n0 + l15, col1 = n0 + 16 + l15;
  const float bv0 = bias[col0], bv1 = bias[col1];
  const int d0 = col0 >= 384, d1 = col1 >= 384;
  const int c0 = col0 - d0*384, c1 = col1 - d1*384;
  #pragma unroll
  for (int r = 0; r < 4; r++){
    const int row = m0 + kg*4 + r;            // frame = b*512 + tt
    const int b = row >> 9, tt = row & 511;
    xwT[((size_t)(d0*512 + tt)*32 + b)*384 + c0] = acc0[r] + bv0;
    xwT[((size_t)(d1*512 + tt)*32 + b)*384 + c1] = acc1[r] + bv1;
  }
}

// ---------------------------------------------------------------------------
// Weight prep: fp32 -> bf16 copies + fused l1-backward bias.
// ---------------------------------------------------------------------------
__global__ __launch_bounds__(256) void prep_kernel(
    const float* __restrict__ g0W, const float* __restrict__ g1W,
    const float* __restrict__ r1Wih,
    const float* __restrict__ r1bih, const float* __restrict__ r1bhh,
    u16* __restrict__ g0o, u16* __restrict__ g1o, u16* __restrict__ r1o,
    float* __restrict__ bo)
{
  const int i = blockIdx.x*256 + threadIdx.x;
  if (i < 196608){ g0o[i] = f2bf(g0W[i]); g1o[i] = f2bf(g1W[i]); }
  if (i < 32768)   r1o[i] = f2bf(r1Wih[32768 + i]);
  if (i < 128)     bo[i]  = r1bih[128+i] + r1bhh[128+i];
}

// ---------------------------------------------------------------------------
// Batched-MFMA GRU recurrence. 4 WGs: (dir, batch-half). 512 thr = 8 waves.
// Per step: G(16,384) = H(16,128)@Whh^T via 12 MFMA/wave; wave w owns
// gate-unit slice u in [16w,16w+16) for ALL 3 gates -> gate math + h-update
// fully in registers. h double-buffered bf16 in LDS (A-fragments). One
// barrier per step. xw read from transposed layout, prefetched 2 steps.
// ---------------------------------------------------------------------------
__global__ __launch_bounds__(512) void gru_mfma(
    const float* __restrict__ xwT,  // (2,512,32,384) f32
    const float* __restrict__ Whh,  // (2,384,128) f32
    const float* __restrict__ bhh,  // (2,384)
    u16* __restrict__ hout)         // (16384,256) bf16
{
  __shared__ __align__(16) u16 h_lds[2][16][136];
  const int t = threadIdx.x;
  const int lane = t & 63, wv = t >> 6;
  const int l15 = lane & 15, kg = lane >> 4;
  const int dir = blockIdx.x & 1, half = blockIdx.x >> 1;
  const int b0 = half*16;
  const int us = wv*16;
  // Whh B-fragments: 3 gates x 4 k-chunks
  s16x8 wb[3][4];
  {
    const float* Wd = Whh + (size_t)dir*49152;
    #pragma unroll
    for (int g = 0; g < 3; g++)
      #pragma unroll
      for (int kc = 0; kc < 4; kc++)
        wb[g][kc] = packfrag(&Wd[(size_t)(g*128 + us + l15)*128 + kc*32 + kg*8]);
  }
  float bh[3];
  #pragma unroll
  for (int g = 0; g < 3; g++) bh[g] = bhh[dir*384 + g*128 + us + l15];
  // zero h buffer 0
  if (t < 272) ((uint4*)&h_lds[0][0][0])[t] = make_uint4(0,0,0,0);
  float hreg[4] = {0.f,0.f,0.f,0.f};
  const float* xwb = xwT + (size_t)dir*512*32*384;
  float px0[4][3], px1[4][3];
#define LOADX(TT, PX)                                                        \
  _Pragma("unroll")                                                          \
  for (int r = 0; r < 4; r++){                                               \
    const float* xp = xwb + ((size_t)(TT)*32 + b0 + kg*4 + r)*384 + us + l15;\
    PX[r][0] = xp[0]; PX[r][1] = xp[128]; PX[r][2] = xp[256];                \
  }
  LOADX(dir ? 511 : 0, px0);
  LOADX(dir ? 510 : 1, px1);
  __syncthreads();
  int cur = 0;

#define GSTEP(TI, PX)                                                        \
  {                                                                          \
    const int tt = dir ? (511-(TI)) : (TI);                                  \
    s16x8 af[4];                                                             \
    _Pragma("unroll")                                                        \
    for (int kc = 0; kc < 4; kc++)                                           \
      af[kc] = *(const s16x8*)&h_lds[cur][l15][kc*32 + kg*8];                \
    f32x4 a0 = {0.f,0.f,0.f,0.f}, a1 = a0, a2 = a0;                          \
    _Pragma("unroll")                                                        \
    for (int kc = 0; kc < 4; kc++){                                          \
      a0 = mfma16(af[kc], wb[0][kc], a0);                                    \
      a1 = mfma16(af[kc], wb[1][kc], a1);                                    \
      a2 = mfma16(af[kc], wb[2][kc], a2);                                    \
    }                                                                        \
    _Pragma("unroll")                                                        \
    for (int r = 0; r < 4; r++){                                             \
      const float rr = fast_sigmoid(PX[r][0] + a0[r] + bh[0]);               \
      const float zz = fast_sigmoid(PX[r][1] + a1[r] + bh[1]);               \
      const float nn = fast_tanh(PX[r][2] + rr*(a2[r] + bh[2]));             \
      const float hn = (1.f - zz)*nn + zz*hreg[r];                           \
      hreg[r] = hn;                                                          \
      const u16 hb = f2bf(hn);                                               \
      h_lds[cur^1][kg*4+r][us + l15] = hb;                                   \
      hout[((size_t)(b0+kg*4+r)*512 + tt)*256 + dir*128 + us + l15] = hb;    \
    }                                                                        \
    { int ti2 = (TI)+2; ti2 = ti2 > 511 ? 511 : ti2;                         \
      const int tn = dir ? (511-ti2) : ti2;                                  \
      LOADX(tn, PX); }                                                       \
    __syncthreads();                                                         \
    cur ^= 1;                                                                \
  }

  for (int ti = 0; ti < 512; ti += 2){
    GSTEP(ti,   px0);
    GSTEP(ti+1, px1);
  }
#undef GSTEP
#undef LOADX
}

__global__ void prefix_kernel(const int* __restrict__ lengths, int* __restrict__ pre){
  if (threadIdx.x == 0 && blockIdx.x == 0){
    int run = 0;
    for (int b = 0; b < 32; b++){ pre[b] = run; run += lengths[b]; }
  }
}

// ---------------------------------------------------------------------------
// Final FC (61 x 256) + ragged masked scatter into d_out (unchanged).
// ---------------------------------------------------------------------------
__global__ __launch_bounds__(256) void fc_kernel(
    const u16* __restrict__ A,      // (16384,256) bf16
    const float* __restrict__ W,    // (61,256)
    const float* __restrict__ bias, // (61)
    const int* __restrict__ lengths,
    const int* __restrict__ pre,
    float* __restrict__ out)
{
  __shared__ __align__(16) float4 Wl[64][61];
  __shared__ __align__(16) float  Al[64][256];
  const int t = threadIdx.x;
  const int row0 = blockIdx.x * 64;
  for (int idx = t; idx < 61*64; idx += 256){
    int c = idx >> 6, k4 = idx & 63;
    Wl[k4][c] = *(const float4*)&W[(size_t)c*256 + k4*4];
  }
  {
    const u32* A32 = (const u32*)(A + (size_t)row0*256);
    for (int idx = t; idx < 8192; idx += 256){
      u32 v = A32[idx];
      int r = idx >> 7, kp = idx & 127;
      Al[r][2*kp]   = bflo(v);
      Al[r][2*kp+1] = bfhi(v);
    }
  }
  __syncthreads();
  const int c = t & 63;
  const int rbase = t >> 6;
  if (c < 61){
    const float bv = bias[c];
    for (int rr = rbase; rr < 64; rr += 4){
      float s0=0,s1=0,s2=0,s3=0;
      const float4* Ap = (const float4*)&Al[rr][0];
      #pragma unroll
      for (int k4 = 0; k4 < 64; k4++){
        const float4 w = Wl[k4][c];
        const float4 a = Ap[k4];
        s0 = fmaf(w.x, a.x, s0);
        s1 = fmaf(w.y, a.y, s1);
        s2 = fmaf(w.z, a.z, s2);
        s3 = fmaf(w.w, a.w, s3);
      }
      const int n = row0 + rr;
      const int b = n >> 9, tt = n & 511;
      if (tt < lengths[b])
        out[(size_t)(pre[b] + tt)*61 + c] = bv + s0+s1+s2+s3;
    }
  }
}

extern "C" void kernel_launch(void* const* d_in, const int* in_sizes, int n_in,
                              void* d_out, int out_size, void* d_ws, size_t ws_size,
                              hipStream_t stream)
{
  const float* x     = (const float*)d_in[0];
  const int*   lens  = (const int*)d_in[1];
  const float* r0Wih = (const float*)d_in[2];
  const float* r0Whh = (const float*)d_in[3];
  const float* r0bih = (const float*)d_in[4];
  const float* r0bhh = (const float*)d_in[5];
  const float* r1Wih = (const float*)d_in[6];
  const float* r1Whh = (const float*)d_in[7];
  const float* r1bih = (const float*)d_in[8];
  const float* r1bhh = (const float*)d_in[9];
  const float* g0Wih = (const float*)d_in[10];
  const float* g0Whh = (const float*)d_in[11];
  const float* g0bih = (const float*)d_in[12];
  const float* g0bhh = (const float*)d_in[13];
  const float* g1Wih = (const float*)d_in[14];
  const float* g1Whh = (const float*)d_in[15];
  const float* g1bih = (const float*)d_in[16];
  const float* g1bhh = (const float*)d_in[17];
  const float* fcW   = (const float*)d_in[18];
  const float* fcb   = (const float*)d_in[19];
  float* out = (float*)d_out;

  char* ws = (char*)d_ws;
  u16*   l0buf = (u16*)(ws);
  float* xwbuf = (float*)(ws);                      // xwT (2,512,32,384) f32
  u16*   g0out = (u16*)(ws + 50331648);
  u16*   g0Wb  = (u16*)(ws + 58720256);             // 393216 B
  u16*   g1Wb  = (u16*)(ws + 58720256 + 393216);    // 393216 B
  u16*   r1Wb  = (u16*)(ws + 58720256 + 786432);    // 65536 B
  float* biasb = (float*)(ws + 58720256 + 851968);  // 512 B
  u16*   g1out = (u16*)(ws + 58720256);             // overwrites prep late
  u16*   rnn1  = (u16*)(ws + 67108864);
  int*   pre   = (int*)(ws + 75497472);

  prep_kernel<<<768, 256, 0, stream>>>(g0Wih, g1Wih, r1Wih, r1bih, r1bhh,
                                       g0Wb, g1Wb, r1Wb, biasb);
  for (int c = 0; c < NF_/CH_; c++){
    l0_mfma<<<dim3(CH_/32, 2), 256, 0, stream>>>(
        x + (size_t)c*CH_*2048, r0Wih, r0Whh, r0bih, r0bhh, l0buf);
    l1f_mfma<<<dim3(CH_/32), 256, 0, stream>>>(
        l0buf, r1Wih, r1Whh, r1bih, r1bhh, rnn1 + (size_t)c*CH_*256);
    mfma_gemm<<<dim3(128/32, CH_/64), 256, 0, stream>>>(
        l0buf + 15*256, 4096, r1Wb, 256, biasb,
        (float*)nullptr, rnn1 + (size_t)c*CH_*256 + 128, 256, 1);
  }
  // GRU layer 0
  gemm_xw<<<dim3(768/32, NF_/64), 256, 0, stream>>>(
      rnn1, 256, g0Wb, 256, g0bih, xwbuf);
  gru_mfma<<<4, 512, 0, stream>>>(xwbuf, g0Whh, g0bhh, g0out);
  // GRU layer 1
  gemm_xw<<<dim3(768/32, NF_/64), 256, 0, stream>>>(
      g0out, 256, g1Wb, 256, g1bih, xwbuf);
  gru_mfma<<<4, 512, 0, stream>>>(xwbuf, g1Whh, g1bhh, g1out);
  // FC + ragged scatter
  prefix_kernel<<<1, 64, 0, stream>>>(lens, pre);
  fc_kernel<<<NF_/64, 256, 0, stream>>>(g1out, fcW, fcb, lens, pre, out);
}

// Round 5
// 1162.723 us; speedup vs baseline: 4.4865x; 1.0181x over previous
//
#include <hip/hip_runtime.h>
#include <hip/hip_bf16.h>

#define B_ 32
#define T_ 512
#define L_ 16
#define F_ 128
#define H_ 128
#define C_ 61
#define NF_ (B_*T_)   // 16384 frames
#define CH_ 4096      // frames per rnn1 chunk

typedef unsigned int u32;
typedef unsigned short u16;
typedef __attribute__((ext_vector_type(8))) short s16x8;
typedef __attribute__((ext_vector_type(4))) float f32x4;

__device__ __forceinline__ float bflo(u32 v){ return __uint_as_float(v << 16); }
__device__ __forceinline__ float bfhi(u32 v){ return __uint_as_float(v & 0xffff0000u); }
__device__ __forceinline__ u16 f2bf(float f){
  u32 u = __float_as_uint(f);
  u += 0x7fffu + ((u >> 16) & 1u);
  return (u16)(u >> 16);
}
__device__ __forceinline__ u32 pack2(float a, float b){
  return (u32)f2bf(a) | ((u32)f2bf(b) << 16);
}
__device__ __forceinline__ float fast_tanh(float x){
  float e = __expf(2.f*x);
  return 1.f - 2.f*__builtin_amdgcn_rcpf(e + 1.f);
}
__device__ __forceinline__ float fast_sigmoid(float x){
  return __builtin_amdgcn_rcpf(1.f + __expf(-x));
}
__device__ __forceinline__ f32x4 mfma16(s16x8 a, s16x8 b, f32x4 c){
  return __builtin_amdgcn_mfma_f32_16x16x32_bf16(a, b, c, 0, 0, 0);
}
// pack 8 consecutive f32 (two float4) into a bf16x8 fragment, k-order
__device__ __forceinline__ s16x8 packfrag(const float* p){
  const float4 a = *(const float4*)p;
  const float4 b = *(const float4*)(p+4);
  union { s16x8 v; u32 w[4]; } f;
  f.w[0]=pack2(a.x,a.y); f.w[1]=pack2(a.z,a.w);
  f.w[2]=pack2(b.x,b.y); f.w[3]=pack2(b.z,b.w);
  return f.v;
}

// ---------------------------------------------------------------------------
// rnn1 layer 0 via MFMA (unchanged)
// ---------------------------------------------------------------------------
__global__ __launch_bounds__(256) void l0_mfma(
    const float* __restrict__ x,      // (CH,16,128) chunk base
    const float* __restrict__ Wih,    // (2,128,128)
    const float* __restrict__ Whh,    // (2,128,128)
    const float* __restrict__ bih,    // (2,128)
    const float* __restrict__ bhh,    // (2,128)
    u16* __restrict__ out)            // (CH,16,256) bf16
{
  __shared__ __align__(16) u16 Hb[2][32][136];
  __shared__ __align__(16) u16 Xb[2][32][136];
  const int t = threadIdx.x;
  const int lane = t & 63, wv = t >> 6;
  const int l15 = lane & 15, kg = lane >> 4;
  const int dir = blockIdx.y;
  const int f0 = blockIdx.x * 32;
  s16x8 wih[2][4], whh[2][4];
  {
    const float* Wid = Wih + dir*16384;
    const float* Whd = Whh + dir*16384;
    #pragma unroll
    for (int nt = 0; nt < 2; nt++){
      const int u = wv*32 + nt*16 + l15;
      #pragma unroll
      for (int kc = 0; kc < 4; kc++){
        const int k = kc*32 + kg*8;
        wih[nt][kc] = packfrag(&Wid[u*128 + k]);
        whh[nt][kc] = packfrag(&Whd[u*128 + k]);
      }
    }
  }
  float bv[2];
  bv[0] = bih[dir*128 + wv*32 + l15]      + bhh[dir*128 + wv*32 + l15];
  bv[1] = bih[dir*128 + wv*32 + 16 + l15] + bhh[dir*128 + wv*32 + 16 + l15];
  const int sr = t >> 3, sc = (t & 7) * 16;
  {
    *(uint4*)&Hb[0][sr][sc]   = make_uint4(0,0,0,0);
    *(uint4*)&Hb[0][sr][sc+8] = make_uint4(0,0,0,0);
    const int s0 = dir ? 15 : 0;
    const float4* xp = (const float4*)&x[(size_t)(f0+sr)*2048 + s0*128 + sc];
    const float4 v0 = xp[0], v1 = xp[1], v2 = xp[2], v3 = xp[3];
    *(uint4*)&Xb[0][sr][sc]   = make_uint4(pack2(v0.x,v0.y),pack2(v0.z,v0.w),
                                           pack2(v1.x,v1.y),pack2(v1.z,v1.w));
    *(uint4*)&Xb[0][sr][sc+8] = make_uint4(pack2(v2.x,v2.y),pack2(v2.z,v2.w),
                                           pack2(v3.x,v3.y),pack2(v3.z,v3.w));
  }
  __syncthreads();
  int cur = 0;
  for (int st = 0; st < 16; st++){
    const int s = dir ? (15-st) : st;
    float4 p0,p1,p2,p3;
    if (st < 15){
      const int sn = dir ? (14-st) : (st+1);
      const float4* xp = (const float4*)&x[(size_t)(f0+sr)*2048 + sn*128 + sc];
      p0 = xp[0]; p1 = xp[1]; p2 = xp[2]; p3 = xp[3];
    }
    f32x4 acc00 = {0.f,0.f,0.f,0.f}, acc01 = acc00, acc10 = acc00, acc11 = acc00;
    #pragma unroll
    for (int kc = 0; kc < 4; kc++){
      const int ko = kc*32 + kg*8;
      const s16x8 ax0 = *(const s16x8*)&Xb[cur][l15][ko];
      const s16x8 ax1 = *(const s16x8*)&Xb[cur][16+l15][ko];
      const s16x8 ah0 = *(const s16x8*)&Hb[cur][l15][ko];
      const s16x8 ah1 = *(const s16x8*)&Hb[cur][16+l15][ko];
      acc00 = mfma16(ax0, wih[0][kc], acc00);
      acc01 = mfma16(ax0, wih[1][kc], acc01);
      acc10 = mfma16(ax1, wih[0][kc], acc10);
      acc11 = mfma16(ax1, wih[1][kc], acc11);
      acc00 = mfma16(ah0, whh[0][kc], acc00);
      acc01 = mfma16(ah0, whh[1][kc], acc01);
      acc10 = mfma16(ah1, whh[0][kc], acc10);
      acc11 = mfma16(ah1, whh[1][kc], acc11);
    }
    const int u0 = wv*32 + l15, u1 = wv*32 + 16 + l15;
    u16* op = out + (size_t)f0*4096 + s*256 + dir*128;
    #pragma unroll
    for (int r = 0; r < 4; r++){
      const int m0r = kg*4 + r, m1r = 16 + kg*4 + r;
      u16 h00 = f2bf(fast_tanh(acc00[r] + bv[0]));
      u16 h01 = f2bf(fast_tanh(acc01[r] + bv[1]));
      u16 h10 = f2bf(fast_tanh(acc10[r] + bv[0]));
      u16 h11 = f2bf(fast_tanh(acc11[r] + bv[1]));
      Hb[cur^1][m0r][u0] = h00;
      Hb[cur^1][m0r][u1] = h01;
      Hb[cur^1][m1r][u0] = h10;
      Hb[cur^1][m1r][u1] = h11;
      op[(size_t)m0r*4096 + u0] = h00;
      op[(size_t)m0r*4096 + u1] = h01;
      op[(size_t)m1r*4096 + u0] = h10;
      op[(size_t)m1r*4096 + u1] = h11;
    }
    if (st < 15){
      *(uint4*)&Xb[cur^1][sr][sc]   = make_uint4(pack2(p0.x,p0.y),pack2(p0.z,p0.w),
                                                 pack2(p1.x,p1.y),pack2(p1.z,p1.w));
      *(uint4*)&Xb[cur^1][sr][sc+8] = make_uint4(pack2(p2.x,p2.y),pack2(p2.z,p2.w),
                                                 pack2(p3.x,p3.y),pack2(p3.z,p3.w));
    }
    __syncthreads();
    cur ^= 1;
  }
}

// ---------------------------------------------------------------------------
// rnn1 layer 1 FORWARD via MFMA. Now 16 frames/WG (grid 256) to fill all CUs.
// ---------------------------------------------------------------------------
__global__ __launch_bounds__(256) void l1f_mfma(
    const u16* __restrict__ U,        // (CH,16,256) bf16
    const float* __restrict__ Wih,    // (2,128,256) dir0
    const float* __restrict__ Whh,    // (2,128,128) dir0
    const float* __restrict__ bih,    // (2,128)
    const float* __restrict__ bhh,
    u16* __restrict__ out)            // rnn1 rows (ld 256), cols 0..127
{
  __shared__ __align__(16) u16 Hb[2][16][136];
  __shared__ __align__(16) u16 Xb[2][16][264];
  const int t = threadIdx.x;
  const int lane = t & 63, wv = t >> 6;
  const int l15 = lane & 15, kg = lane >> 4;
  const int f0 = blockIdx.x * 16;
  s16x8 wih[2][8], whh[2][4];
  {
    #pragma unroll
    for (int nt = 0; nt < 2; nt++){
      const int u = wv*32 + nt*16 + l15;
      #pragma unroll
      for (int kc = 0; kc < 8; kc++)
        wih[nt][kc] = packfrag(&Wih[u*256 + kc*32 + kg*8]);
      #pragma unroll
      for (int kc = 0; kc < 4; kc++)
        whh[nt][kc] = packfrag(&Whh[u*128 + kc*32 + kg*8]);
    }
  }
  float bv[2];
  bv[0] = bih[wv*32 + l15]      + bhh[wv*32 + l15];
  bv[1] = bih[wv*32 + 16 + l15] + bhh[wv*32 + 16 + l15];
  const int sr = t >> 4, scu = (t & 15) * 16;   // 16 rows, 32B per thread
  for (int idx = t; idx < 272; idx += 256)
    ((uint4*)&Hb[0][0][0])[idx] = make_uint4(0,0,0,0);
  {
    const uint4* up = (const uint4*)&U[(size_t)(f0+sr)*4096 + scu];
    uint4 c0 = up[0], c1 = up[1];
    *(uint4*)&Xb[0][sr][scu]   = c0;
    *(uint4*)&Xb[0][sr][scu+8] = c1;
  }
  __syncthreads();
  int cur = 0;
  for (int st = 0; st < 16; st++){
    uint4 c0,c1;
    if (st < 15){
      const uint4* up = (const uint4*)&U[(size_t)(f0+sr)*4096 + (st+1)*256 + scu];
      c0 = up[0]; c1 = up[1];
    }
    f32x4 acc0 = {0.f,0.f,0.f,0.f}, acc1 = acc0;
    #pragma unroll
    for (int kc = 0; kc < 8; kc++){
      const s16x8 ax = *(const s16x8*)&Xb[cur][l15][kc*32 + kg*8];
      acc0 = mfma16(ax, wih[0][kc], acc0);
      acc1 = mfma16(ax, wih[1][kc], acc1);
    }
    #pragma unroll
    for (int kc = 0; kc < 4; kc++){
      const s16x8 ah = *(const s16x8*)&Hb[cur][l15][kc*32 + kg*8];
      acc0 = mfma16(ah, whh[0][kc], acc0);
      acc1 = mfma16(ah, whh[1][kc], acc1);
    }
    const int u0 = wv*32 + l15, u1 = wv*32 + 16 + l15;
    #pragma unroll
    for (int r = 0; r < 4; r++){
      const int m = kg*4 + r;
      const u16 h0 = f2bf(fast_tanh(acc0[r] + bv[0]));
      const u16 h1 = f2bf(fast_tanh(acc1[r] + bv[1]));
      Hb[cur^1][m][u0] = h0;
      Hb[cur^1][m][u1] = h1;
      if (st == 15){
        out[(size_t)(f0+m)*256 + u0] = h0;
        out[(size_t)(f0+m)*256 + u1] = h1;
      }
    }
    if (st < 15){
      *(uint4*)&Xb[cur^1][sr][scu]   = c0;
      *(uint4*)&Xb[cur^1][sr][scu+8] = c1;
    }
    __syncthreads();
    cur ^= 1;
  }
}

// ---------------------------------------------------------------------------
// Register-only MFMA GEMM: C(M,N) = A @ Wb^T + bias [tanh], bf16/f32 out.
// ---------------------------------------------------------------------------
__global__ __launch_bounds__(256) void mfma_gemm(
    const u16* __restrict__ A, int lda,
    const u16* __restrict__ Wb, int K,
    const float* __restrict__ bias,
    float* __restrict__ Cf, u16* __restrict__ Cb, int ldc, int act)
{
  const int t = threadIdx.x;
  const int lane = t & 63, wv = t >> 6;
  const int l15 = lane & 15, kg = lane >> 4;
  const int n0 = blockIdx.x * 32;
  const int m0 = blockIdx.y * 64 + wv*16;
  const u16* Ap = A + (size_t)(m0 + l15)*lda + kg*8;
  const u16* W0 = Wb + (size_t)(n0 + l15)*K + kg*8;
  const u16* W1 = Wb + (size_t)(n0 + 16 + l15)*K + kg*8;
  f32x4 acc0 = {0.f,0.f,0.f,0.f}, acc1 = acc0;
  #pragma unroll 4
  for (int kc = 0; kc < K/32; kc++){
    const s16x8 a  = *(const s16x8*)(Ap + kc*32);
    const s16x8 b0 = *(const s16x8*)(W0 + kc*32);
    const s16x8 b1 = *(const s16x8*)(W1 + kc*32);
    acc0 = mfma16(a, b0, acc0);
    acc1 = mfma16(a, b1, acc1);
  }
  const int col0 = n0 + l15, col1 = n0 + 16 + l15;
  const float bv0 = bias[col0], bv1 = bias[col1];
  #pragma unroll
  for (int r = 0; r < 4; r++){
    const int row = m0 + kg*4 + r;
    float v0 = acc0[r] + bv0, v1 = acc1[r] + bv1;
    if (act){ v0 = fast_tanh(v0); v1 = fast_tanh(v1); }
    if (Cf){
      Cf[(size_t)row*ldc + col0] = v0;
      Cf[(size_t)row*ldc + col1] = v1;
    } else {
      Cb[(size_t)row*ldc + col0] = f2bf(v0);
      Cb[(size_t)row*ldc + col1] = f2bf(v1);
    }
  }
}

// ---------------------------------------------------------------------------
// xw GEMM: stores into gru-native layout:
// idx(d,tt,b,g,u) = ((((d*512+tt)*2 + b/16)*8 + u/16)*4 + (b%16)/4)*192
//                   + (u%16)*12 + g*4 + b%4
// so each gru thread's 12 floats are contiguous (48B).
// ---------------------------------------------------------------------------
__global__ __launch_bounds__(256) void gemm_xw(
    const u16* __restrict__ A, int lda,
    const u16* __restrict__ Wb, int K,
    const float* __restrict__ bias,
    float* __restrict__ xwT)
{
  const int t = threadIdx.x;
  const int lane = t & 63, wv = t >> 6;
  const int l15 = lane & 15, kg = lane >> 4;
  const int n0 = blockIdx.x * 32;
  const int m0 = blockIdx.y * 64 + wv*16;
  const u16* Ap = A + (size_t)(m0 + l15)*lda + kg*8;
  const u16* W0 = Wb + (size_t)(n0 + l15)*K + kg*8;
  const u16* W1 = Wb + (size_t)(n0 + 16 + l15)*K + kg*8;
  f32x4 acc0 = {0.f,0.f,0.f,0.f}, acc1 = acc0;
  #pragma unroll 4
  for (int kc = 0; kc < K/32; kc++){
    const s16x8 a  = *(const s16x8*)(Ap + kc*32);
    const s16x8 b0 = *(const s16x8*)(W0 + kc*32);
    const s16x8 b1 = *(const s16x8*)(W1 + kc*32);
    acc0 = mfma16(a, b0, acc0);
    acc1 = mfma16(a, b1, acc1);
  }
  const int col0 = n0 + l15, col1 = n0 + 16 + l15;
  const float bv0 = bias[col0], bv1 = bias[col1];
  const int row0 = m0 + kg*4;
  const int b   = row0 >> 9;         // same for all 4 rows (16-aligned)
  const int tt0 = row0 & 511;
  const int half = b >> 4, kg2 = (b & 15) >> 2, r2 = b & 3;
  const int d0 = col0 >= 384, d1 = col1 >= 384;
  const int cc0 = col0 - d0*384, cc1 = col1 - d1*384;
  const size_t i0 = (((((size_t)d0*512 + tt0)*2 + half)*8 + (cc0>>7? 0:0) + ((cc0&127)>>4))*4 + kg2)*192
                    + (size_t)(cc0&15)*12 + (cc0>>7)*4 + r2;
  const size_t i1 = (((((size_t)d1*512 + tt0)*2 + half)*8 + ((cc1&127)>>4))*4 + kg2)*192
                    + (size_t)(cc1&15)*12 + (cc1>>7)*4 + r2;
  #pragma unroll
  for (int r = 0; r < 4; r++){
    xwT[i0 + (size_t)r*12288] = acc0[r] + bv0;
    xwT[i1 + (size_t)r*12288] = acc1[r] + bv1;
  }
}

// ---------------------------------------------------------------------------
// Weight prep: fp32 -> bf16 copies + fused l1-backward bias.
// ---------------------------------------------------------------------------
__global__ __launch_bounds__(256) void prep_kernel(
    const float* __restrict__ g0W, const float* __restrict__ g1W,
    const float* __restrict__ r1Wih,
    const float* __restrict__ r1bih, const float* __restrict__ r1bhh,
    u16* __restrict__ g0o, u16* __restrict__ g1o, u16* __restrict__ r1o,
    float* __restrict__ bo)
{
  const int i = blockIdx.x*256 + threadIdx.x;
  if (i < 196608){ g0o[i] = f2bf(g0W[i]); g1o[i] = f2bf(g1W[i]); }
  if (i < 32768)   r1o[i] = f2bf(r1Wih[32768 + i]);
  if (i < 128)     bo[i]  = r1bih[128+i] + r1bhh[128+i];
}

// ---------------------------------------------------------------------------
// Batched-MFMA GRU recurrence v2. 4 WGs (dir, half). 512 thr = 8 waves.
// xw in gru-native layout -> 3 dwordx4 per thread per step off one marching
// pointer; hout via 4 int offsets marching +-256; gate math in registers.
// ---------------------------------------------------------------------------
__global__ __launch_bounds__(512) void gru_mfma(
    const float* __restrict__ xwT,  // (2,512,12288) gru-native
    const float* __restrict__ Whh,  // (2,384,128) f32
    const float* __restrict__ bhh,  // (2,384)
    u16* __restrict__ hout)         // (16384,256) bf16
{
  __shared__ __align__(16) u16 h_lds[2][16][136];
  const int t = threadIdx.x;
  const int lane = t & 63, wv = t >> 6;
  const int l15 = lane & 15, kg = lane >> 4;
  const int dir = blockIdx.x & 1, half = blockIdx.x >> 1;
  const int b0 = half*16;
  const int us = wv*16;
  s16x8 wb[3][4];
  {
    const float* Wd = Whh + (size_t)dir*49152;
    #pragma unroll
    for (int g = 0; g < 3; g++)
      #pragma unroll
      for (int kc = 0; kc < 4; kc++)
        wb[g][kc] = packfrag(&Wd[(size_t)(g*128 + us + l15)*128 + kc*32 + kg*8]);
  }
  const float bh0 = bhh[dir*384 + us + l15];
  const float bh1 = bhh[dir*384 + 128 + us + l15];
  const float bh2 = bhh[dir*384 + 256 + us + l15];
  if (t < 272) ((uint4*)&h_lds[0][0][0])[t] = make_uint4(0,0,0,0);
  float hreg[4] = {0.f,0.f,0.f,0.f};
  const long tstep = dir ? -49152 : 49152;       // bytes per tt step
  const char* xb = (const char*)xwT
      + ((size_t)dir*512 + (dir ? 511 : 0))*49152
      + (size_t)((((half*8 + wv)*4 + kg)*16 + l15)*12)*4;
  f32x4 px0[3], px1[3];
  px0[0] = *(const f32x4*)(xb); px0[1] = *(const f32x4*)(xb+16); px0[2] = *(const f32x4*)(xb+32);
  xb += tstep;
  px1[0] = *(const f32x4*)(xb); px1[1] = *(const f32x4*)(xb+16); px1[2] = *(const f32x4*)(xb+32);
  xb += tstep;
  const int hstep = dir ? -256 : 256;            // u16 units per tt step
  int hoff[4];
  #pragma unroll
  for (int r = 0; r < 4; r++)
    hoff[r] = ((b0 + kg*4 + r)*512 + (dir ? 511 : 0))*256 + dir*128 + us + l15;
  __syncthreads();
  int cur = 0;

#define GSTEP(PX)                                                           \
  {                                                                         \
    const s16x8 af0 = *(const s16x8*)&h_lds[cur][l15][kg*8];                \
    const s16x8 af1 = *(const s16x8*)&h_lds[cur][l15][32+kg*8];             \
    const s16x8 af2 = *(const s16x8*)&h_lds[cur][l15][64+kg*8];             \
    const s16x8 af3 = *(const s16x8*)&h_lds[cur][l15][96+kg*8];             \
    f32x4 a0 = {0.f,0.f,0.f,0.f}, a1 = a0, a2 = a0;                         \
    a0 = mfma16(af0, wb[0][0], a0);                                         \
    a1 = mfma16(af0, wb[1][0], a1);                                         \
    a2 = mfma16(af0, wb[2][0], a2);                                         \
    a0 = mfma16(af1, wb[0][1], a0);                                         \
    a1 = mfma16(af1, wb[1][1], a1);                                         \
    a2 = mfma16(af1, wb[2][1], a2);                                         \
    a0 = mfma16(af2, wb[0][2], a0);                                         \
    a1 = mfma16(af2, wb[1][2], a1);                                         \
    a2 = mfma16(af2, wb[2][2], a2);                                         \
    a0 = mfma16(af3, wb[0][3], a0);                                         \
    a1 = mfma16(af3, wb[1][3], a1);                                         \
    a2 = mfma16(af3, wb[2][3], a2);                                         \
    const f32x4 n0 = *(const f32x4*)(xb);                                   \
    const f32x4 n1 = *(const f32x4*)(xb+16);                                \
    const f32x4 n2 = *(const f32x4*)(xb+32);                                \
    xb += tstep;                                                            \
    _Pragma("unroll")                                                       \
    for (int r = 0; r < 4; r++){                                            \
      const float rr = fast_sigmoid(PX[0][r] + a0[r] + bh0);                \
      const float zz = fast_sigmoid(PX[1][r] + a1[r] + bh1);                \
      const float nn = fast_tanh(PX[2][r] + rr*(a2[r] + bh2));              \
      const float hn = fmaf(zz, hreg[r]-nn, nn);                            \
      hreg[r] = hn;                                                         \
      const u16 hb = f2bf(hn);                                              \
      h_lds[cur^1][kg*4+r][us+l15] = hb;                                    \
      hout[hoff[r]] = hb;                                                   \
      hoff[r] += hstep;                                                     \
    }                                                                       \
    PX[0] = n0; PX[1] = n1; PX[2] = n2;                                     \
    __syncthreads();                                                        \
    cur ^= 1;                                                               \
  }

  for (int ti = 0; ti < 512; ti += 2){
    GSTEP(px0);
    GSTEP(px1);
  }
#undef GSTEP
}

__global__ void prefix_kernel(const int* __restrict__ lengths, int* __restrict__ pre){
  if (threadIdx.x == 0 && blockIdx.x == 0){
    int run = 0;
    for (int b = 0; b < 32; b++){ pre[b] = run; run += lengths[b]; }
  }
}

// ---------------------------------------------------------------------------
// Final FC (61 x 256) + ragged masked scatter into d_out (unchanged).
// ---------------------------------------------------------------------------
__global__ __launch_bounds__(256) void fc_kernel(
    const u16* __restrict__ A,      // (16384,256) bf16
    const float* __restrict__ W,    // (61,256)
    const float* __restrict__ bias, // (61)
    const int* __restrict__ lengths,
    const int* __restrict__ pre,
    float* __restrict__ out)
{
  __shared__ __align__(16) float4 Wl[64][61];
  __shared__ __align__(16) float  Al[64][256];
  const int t = threadIdx.x;
  const int row0 = blockIdx.x * 64;
  for (int idx = t; idx < 61*64; idx += 256){
    int c = idx >> 6, k4 = idx & 63;
    Wl[k4][c] = *(const float4*)&W[(size_t)c*256 + k4*4];
  }
  {
    const u32* A32 = (const u32*)(A + (size_t)row0*256);
    for (int idx = t; idx < 8192; idx += 256){
      u32 v = A32[idx];
      int r = idx >> 7, kp = idx & 127;
      Al[r][2*kp]   = bflo(v);
      Al[r][2*kp+1] = bfhi(v);
    }
  }
  __syncthreads();
  const int c = t & 63;
  const int rbase = t >> 6;
  if (c < 61){
    const float bv = bias[c];
    for (int rr = rbase; rr < 64; rr += 4){
      float s0=0,s1=0,s2=0,s3=0;
      const float4* Ap = (const float4*)&Al[rr][0];
      #pragma unroll
      for (int k4 = 0; k4 < 64; k4++){
        const float4 w = Wl[k4][c];
        const float4 a = Ap[k4];
        s0 = fmaf(w.x, a.x, s0);
        s1 = fmaf(w.y, a.y, s1);
        s2 = fmaf(w.z, a.z, s2);
        s3 = fmaf(w.w, a.w, s3);
      }
      const int n = row0 + rr;
      const int b = n >> 9, tt = n & 511;
      if (tt < lengths[b])
        out[(size_t)(pre[b] + tt)*61 + c] = bv + s0+s1+s2+s3;
    }
  }
}

extern "C" void kernel_launch(void* const* d_in, const int* in_sizes, int n_in,
                              void* d_out, int out_size, void* d_ws, size_t ws_size,
                              hipStream_t stream)
{
  const float* x     = (const float*)d_in[0];
  const int*   lens  = (const int*)d_in[1];
  const float* r0Wih = (const float*)d_in[2];
  const float* r0Whh = (const float*)d_in[3];
  const float* r0bih = (const float*)d_in[4];
  const float* r0bhh = (const float*)d_in[5];
  const float* r1Wih = (const float*)d_in[6];
  const float* r1Whh = (const float*)d_in[7];
  const float* r1bih = (const float*)d_in[8];
  const float* r1bhh = (const float*)d_in[9];
  const float* g0Wih = (const float*)d_in[10];
  const float* g0Whh = (const float*)d_in[11];
  const float* g0bih = (const float*)d_in[12];
  const float* g0bhh = (const float*)d_in[13];
  const float* g1Wih = (const float*)d_in[14];
  const float* g1Whh = (const float*)d_in[15];
  const float* g1bih = (const float*)d_in[16];
  const float* g1bhh = (const float*)d_in[17];
  const float* fcW   = (const float*)d_in[18];
  const float* fcb   = (const float*)d_in[19];
  float* out = (float*)d_out;

  char* ws = (char*)d_ws;
  u16*   l0buf = (u16*)(ws);
  float* xwbuf = (float*)(ws);                      // xwT (2,512,12288) f32
  u16*   g0out = (u16*)(ws + 50331648);
  u16*   g0Wb  = (u16*)(ws + 58720256);             // 393216 B
  u16*   g1Wb  = (u16*)(ws + 58720256 + 393216);    // 393216 B
  u16*   r1Wb  = (u16*)(ws + 58720256 + 786432);    // 65536 B
  float* biasb = (float*)(ws + 58720256 + 851968);  // 512 B
  u16*   g1out = (u16*)(ws + 58720256);             // overwrites prep late
  u16*   rnn1  = (u16*)(ws + 67108864);
  int*   pre   = (int*)(ws + 75497472);

  prep_kernel<<<768, 256, 0, stream>>>(g0Wih, g1Wih, r1Wih, r1bih, r1bhh,
                                       g0Wb, g1Wb, r1Wb, biasb);
  for (int c = 0; c < NF_/CH_; c++){
    l0_mfma<<<dim3(CH_/32, 2), 256, 0, stream>>>(
        x + (size_t)c*CH_*2048, r0Wih, r0Whh, r0bih, r0bhh, l0buf);
    l1f_mfma<<<dim3(CH_/16), 256, 0, stream>>>(
        l0buf, r1Wih, r1Whh, r1bih, r1bhh, rnn1 + (size_t)c*CH_*256);
    mfma_gemm<<<dim3(128/32, CH_/64), 256, 0, stream>>>(
        l0buf + 15*256, 4096, r1Wb, 256, biasb,
        (float*)nullptr, rnn1 + (size_t)c*CH_*256 + 128, 256, 1);
  }
  // GRU layer 0
  gemm_xw<<<dim3(768/32, NF_/64), 256, 0, stream>>>(
      rnn1, 256, g0Wb, 256, g0bih, xwbuf);
  gru_mfma<<<4, 512, 0, stream>>>(xwbuf, g0Whh, g0bhh, g0out);
  // GRU layer 1
  gemm_xw<<<dim3(768/32, NF_/64), 256, 0, stream>>>(
      g0out, 256, g1Wb, 256, g1bih, xwbuf);
  gru_mfma<<<4, 512, 0, stream>>>(xwbuf, g1Whh, g1bhh, g1out);
  // FC + ragged scatter
  prefix_kernel<<<1, 64, 0, stream>>>(lens, pre);
  fc_kernel<<<NF_/64, 256, 0, stream>>>(g1out, fcW, fcb, lens, pre, out);
}